// Round 2
// baseline (548.992 us; speedup 1.0000x reference)
//
#include <hip/hip_runtime.h>
#include <hip/hip_bf16.h>

typedef __attribute__((ext_vector_type(8))) short bf16x8;
typedef __attribute__((ext_vector_type(4))) float f32x4;
typedef __attribute__((ext_vector_type(4))) unsigned u32x4;

__device__ __forceinline__ unsigned bfbits(float v) {
  __hip_bfloat16 h = __float2bfloat16(v);
  return (unsigned)*reinterpret_cast<unsigned short*>(&h);
}

// ---------------------------------------------------------------------------
// Kernel 1: normalize weight rows (exact fp32), write bf16, K reordered to
// (kh*3+kw)*64 + c so that c (64 wide) is the contiguous MFMA-K inner dim.
// ---------------------------------------------------------------------------
__global__ void wnorm_kernel(const float* __restrict__ w,
                             ushort* __restrict__ wt) {
  const int o = blockIdx.x;    // 0..255
  const int c = threadIdx.x;   // 0..63
  float v[9];
  float ss = 0.f;
  const float* row = w + o * 576 + c * 9;
#pragma unroll
  for (int j = 0; j < 9; ++j) { v[j] = row[j]; ss += v[j] * v[j]; }
#pragma unroll
  for (int off = 32; off > 0; off >>= 1) ss += __shfl_xor(ss, off);
  const float inv = 1.0f / fmaxf(sqrtf(ss), 1e-12f);
#pragma unroll
  for (int j = 0; j < 9; ++j)
    wt[o * 576 + j * 64 + c] = (ushort)bfbits(v[j] * inv);
}

// ---------------------------------------------------------------------------
// Kernel 2: transpose+convert x [B][C][H][W] fp32 -> xt [B][H][W][C] bf16,
// and css[B][H][W] = sum_c x^2 (fp32, exact). One block per (y, b).
// ---------------------------------------------------------------------------
__global__ __launch_bounds__(256, 8) void xprep_kernel(
    const float* __restrict__ x, ushort* __restrict__ xt,
    float* __restrict__ css) {
  __shared__ __align__(16) unsigned tile[64 * 33];  // [x][c2] padded stride 33
  __shared__ __align__(16) float cssp[4 * 64];
  const int t = threadIdx.x;
  const int y = blockIdx.x, b = blockIdx.y;
  const int c = t >> 2, m = t & 3;
  const int lane = t & 63, w = t >> 6;

  // load 16 floats of row (b,c,y): x-positions px(j) = (j>>2)*16 + m*4 + (j&3)
  const float* src = x + (((size_t)b * 64 + c) * 64 + y) * 64 + m * 4;
  float f[16];
#pragma unroll
  for (int j4 = 0; j4 < 4; ++j4) {
    const f32x4 v = *(const f32x4*)(src + j4 * 16);
#pragma unroll
    for (int k = 0; k < 4; ++k) f[j4 * 4 + k] = v[k];
  }
  // sum of squares over c: lanes stride 4 (16 c per wave), then across 4 waves
  float s[16];
#pragma unroll
  for (int j = 0; j < 16; ++j) {
    float v = f[j] * f[j];
    v += __shfl_xor(v, 4);
    v += __shfl_xor(v, 8);
    v += __shfl_xor(v, 16);
    v += __shfl_xor(v, 32);
    s[j] = v;
  }
  if (lane < 4) {
#pragma unroll
    for (int j4 = 0; j4 < 4; ++j4) {
      f32x4 v = {s[j4 * 4], s[j4 * 4 + 1], s[j4 * 4 + 2], s[j4 * 4 + 3]};
      *(f32x4*)(cssp + w * 64 + j4 * 16 + lane * 4) = v;
    }
  }
  // pack (c even, c odd) bf16 pairs via lane exchange, write transposed tile
  const int parity = c & 1;
  const int c2 = c >> 1;
#pragma unroll
  for (int j = 0; j < 16; ++j) {
    const float pf = __shfl_xor(f[j], 4);  // partner c^1, same x
    const bool mine = parity ? (j >= 8) : (j < 8);
    if (mine) {
      const unsigned dw = parity ? (bfbits(pf) | (bfbits(f[j]) << 16))
                                 : (bfbits(f[j]) | (bfbits(pf) << 16));
      const int px = (j >> 2) * 16 + m * 4 + (j & 3);
      tile[px * 33 + c2] = dw;
    }
  }
  __syncthreads();
  // read back x-major (c contiguous) and store xt coalesced
  {
    const int xr = t >> 2, q = t & 3;
    unsigned d[8];
#pragma unroll
    for (int i = 0; i < 8; ++i) d[i] = tile[xr * 33 + q * 8 + i];
    ushort* dst = xt + (((size_t)b * 64 + y) * 64 + xr) * 64 + q * 16;
    u32x4 v0 = {d[0], d[1], d[2], d[3]};
    u32x4 v1 = {d[4], d[5], d[6], d[7]};
    *(u32x4*)dst = v0;
    *(u32x4*)(dst + 8) = v1;
  }
  if (t < 64) {
    const float sum = cssp[t] + cssp[64 + t] + cssp[128 + t] + cssp[192 + t];
    css[((size_t)b * 64 + y) * 64 + t] = sum;
  }
}

// ---------------------------------------------------------------------------
// Kernel 3: invp[b][y][x] = 1/(sqrt(3x3 window sum of css)+1e-8)
// ---------------------------------------------------------------------------
__global__ void invp_kernel(const float* __restrict__ css,
                            float* __restrict__ invp) {
  const int xx = threadIdx.x;  // 0..63
  const int y = blockIdx.x, b = blockIdx.y;
  float s = 0.f;
#pragma unroll
  for (int dy = -1; dy <= 1; ++dy) {
    const int yy = y + dy;
    if ((unsigned)yy < 64u) s += css[((size_t)b * 64 + yy) * 64 + xx];
  }
  const float sl = __shfl_up(s, 1);
  const float sr = __shfl_down(s, 1);
  const float tot = s + ((xx > 0) ? sl : 0.f) + ((xx < 63) ? sr : 0.f);
  invp[((size_t)b * 64 + y) * 64 + xx] =
      1.0f / (sqrtf(fmaxf(tot, 0.f)) + 1e-8f);
}

// ---------------------------------------------------------------------------
// Main kernel: one block per (image b, output row-pair y0). Stages bf16 rows
// from xt via global_load_lds (pre-swizzled source, linear LDS dest), MFMA
// GEMM M=128 x N=256 x K=576, exp epilogue, 2x2 pool, coalesced store.
//
// LDS: xs [4][66][128B] swizzled (byte ^= (col&7)<<4) at [0,33792)
//      pool float[256][36] aliases [0,36864)
//      invp float[128] at [36864,37376)
// ---------------------------------------------------------------------------
__global__ __launch_bounds__(512, 8) void ckn_main(
    const ushort* __restrict__ xt, const float* __restrict__ invp_g,
    const ushort* __restrict__ wt, float* __restrict__ out) {
  __shared__ __align__(16) char smem[37376];
  char* const xs = smem;
  float* const pool = (float*)smem;
  float* const invp = (float*)(smem + 36864);

  const int tid = threadIdx.x;
  const int y0 = blockIdx.x;
  const int b = blockIdx.y;

  // pad columns (col 0 and 65, all 4 rows)
  if (tid < 64) {
    const int r4 = tid >> 4, colsel = (tid >> 3) & 1, cblk = tid & 7;
    *(f32x4*)(xs + r4 * 8448 + colsel * 65 * 128 + cblk * 16) =
        (f32x4){0.f, 0.f, 0.f, 0.f};
  }
  if (tid < 128)
    invp[tid] = invp_g[((size_t)b * 64 + 2 * y0 + (tid >> 6)) * 64 + (tid & 63)];

  // stage 4 rows: one 16B global_load_lds per thread per row.
  // LDS dest linear; source address carries the inverse XOR swizzle.
  {
    const int xx = tid >> 3;
    const int c0 = 8 * ((tid & 7) ^ ((xx + 1) & 7));
    const ushort* srcb = xt + ((size_t)b * 64) * 4096 + (size_t)xx * 64 + c0;
#pragma unroll
    for (int r4 = 0; r4 < 4; ++r4) {
      const int y_img = 2 * y0 - 1 + r4;
      char* dst = xs + r4 * 8448 + 128 + tid * 16;
      if ((unsigned)y_img < 64u) {
        const ushort* src = srcb + (size_t)y_img * 4096;
        __builtin_amdgcn_global_load_lds(
            (const __attribute__((address_space(1))) void*)src,
            (__attribute__((address_space(3))) void*)dst, 16, 0, 0);
      } else {
        *(f32x4*)dst = (f32x4){0.f, 0.f, 0.f, 0.f};
      }
    }
  }
  __syncthreads();

  // K-loop GEMM: 8 waves = 2(M) x 4(N), wave tile 64x64
  const int lane = tid & 63;
  const int wid = tid >> 6;
  const int wave_m = wid & 1;
  const int wave_n = wid >> 1;
  const int lane16 = lane & 15;
  const int klane = lane >> 4;
  const int o_base = wave_n * 64;

  f32x4 acc[4][4];
#pragma unroll
  for (int i = 0; i < 4; ++i)
#pragma unroll
    for (int j = 0; j < 4; ++j) acc[i][j] = (f32x4){0.f, 0.f, 0.f, 0.f};

  const ushort* wbase = wt + (o_base + lane16) * 576 + klane * 8;

#pragma unroll
  for (int ks = 0; ks < 18; ++ks) {
    const int t9 = ks >> 1;
    const int kh = t9 / 3, kw = t9 % 3;
    const int cb = (ks & 1) * 64 + klane * 16;
    bf16x8 bfrag[4];
#pragma unroll
    for (int fn = 0; fn < 4; ++fn)
      bfrag[fn] = *(const bf16x8*)(wbase + fn * 16 * 576 + ks * 32);
    const int r4 = wave_m + kh;
#pragma unroll
    for (int fm = 0; fm < 4; ++fm) {
      const int col = fm * 16 + lane16 + kw;
      const int addr = r4 * 8448 + col * 128 + (cb ^ ((col & 7) << 4));
      const bf16x8 afrag = *(const bf16x8*)(xs + addr);
#pragma unroll
      for (int fn = 0; fn < 4; ++fn)
        acc[fm][fn] = __builtin_amdgcn_mfma_f32_16x16x32_bf16(
            afrag, bfrag[fn], acc[fm][fn], 0, 0, 0);
    }
  }

  // epilogue: exp(cos-1), x-pool in-register
  float ep0[4][4], ep1[4][4];
#pragma unroll
  for (int fm = 0; fm < 4; ++fm) {
    const int mrow = wave_m * 64 + fm * 16 + klane * 4;
    const f32x4 ip = *(const f32x4*)(invp + mrow);
#pragma unroll
    for (int fn = 0; fn < 4; ++fn) {
      const f32x4 v = acc[fm][fn];
      const float e0 = __expf(v[0] * ip[0] - 1.f);
      const float e1 = __expf(v[1] * ip[1] - 1.f);
      const float e2 = __expf(v[2] * ip[2] - 1.f);
      const float e3 = __expf(v[3] * ip[3] - 1.f);
      ep0[fm][fn] = e0 + e1;
      ep1[fm][fn] = e2 + e3;
    }
  }
  __syncthreads();  // xs reads done; pool may alias

  if (wave_m == 1) {
#pragma unroll
    for (int fm = 0; fm < 4; ++fm) {
      const int ox = fm * 8 + klane * 2;
#pragma unroll
      for (int fn = 0; fn < 4; ++fn) {
        const int o = o_base + fn * 16 + lane16;
        *(float2*)(pool + o * 36 + ox) = make_float2(ep0[fm][fn], ep1[fm][fn]);
      }
    }
  }
  __syncthreads();
  if (wave_m == 0) {
#pragma unroll
    for (int fm = 0; fm < 4; ++fm) {
      const int ox = fm * 8 + klane * 2;
#pragma unroll
      for (int fn = 0; fn < 4; ++fn) {
        const int o = o_base + fn * 16 + lane16;
        float2* p = (float2*)(pool + o * 36 + ox);
        const float2 othr = *p;
        *p = make_float2(0.25f * (ep0[fm][fn] + othr.x),
                         0.25f * (ep1[fm][fn] + othr.y));
      }
    }
  }
  __syncthreads();

  // coalesced store: 8 lanes cover one o-row's full 128B
  const size_t obase = (((size_t)b * 256) * 32 + y0) * 32;
#pragma unroll
  for (int j = 0; j < 4; ++j) {
    const int o = j * 64 + (tid >> 3);
    const int ch = (tid & 7) * 4;
    const f32x4 v = *(const f32x4*)(pool + o * 36 + ch);
    *(f32x4*)(out + obase + (size_t)o * 1024 + ch) = v;
  }
}

// ---------------------------------------------------------------------------
// Fallback (round-1 kernel, fused transpose in-block) if ws is too small.
// ---------------------------------------------------------------------------
__global__ __launch_bounds__(512, 4) void ckn_main_v1(
    const float* __restrict__ x, const ushort* __restrict__ wt,
    float* __restrict__ out) {
  __shared__ __align__(16) char smem[43552];
  char* const xs = smem;
  float* const invp = (float*)(smem + 33792);
  float* const cs = (float*)(smem + 34304);
  float* const csp = (float*)(smem + 35360);
  float* const pool = (float*)smem;

  const int tid = threadIdx.x;
  const int y0 = blockIdx.x;
  const int b = blockIdx.y;

  if (tid < 64) {
    const int r4 = tid >> 4, colsel = (tid >> 3) & 1, cblk = tid & 7;
    const int col = colsel * 65;
    *(f32x4*)(xs + r4 * 8448 + col * 128 + cblk * 16) =
        (f32x4){0.f, 0.f, 0.f, 0.f};
  }
  {
    const int xx = tid & 63;
    const int cg = tid >> 6;
    const int col = xx + 1;
    const int sw = (cg * 16) ^ ((col & 7) << 4);
#pragma unroll
    for (int r4 = 0; r4 < 4; ++r4) {
      const int y_img = 2 * y0 - 1 + r4;
      char* dst = xs + r4 * 8448 + col * 128 + sw;
      if ((unsigned)y_img < 64u) {
        const float* src =
            x + (((size_t)b * 64 + cg * 8) * 64 + y_img) * 64 + xx;
        float ss = 0.f;
        union { bf16x8 v; ushort u[8]; } pk;
#pragma unroll
        for (int j = 0; j < 8; ++j) {
          const float f = src[(size_t)j * 4096];
          ss += f * f;
          pk.u[j] = (ushort)bfbits(f);
        }
        *(bf16x8*)dst = pk.v;
        csp[(r4 * 8 + cg) * 64 + xx] = ss;
      } else {
        *(bf16x8*)dst = (bf16x8){0, 0, 0, 0, 0, 0, 0, 0};
        csp[(r4 * 8 + cg) * 64 + xx] = 0.f;
      }
    }
  }
  __syncthreads();
  if (tid < 256) {
    const int r4 = tid >> 6, xc = tid & 63;
    float s = 0.f;
#pragma unroll
    for (int cg = 0; cg < 8; ++cg) s += csp[(r4 * 8 + cg) * 64 + xc];
    cs[r4 * 66 + xc + 1] = s;
  }
  if (tid >= 256 && tid < 264) {
    const int t = tid - 256;
    cs[(t >> 1) * 66 + (t & 1) * 65] = 0.f;
  }
  __syncthreads();
  if (tid < 128) {
    const int ry = tid >> 6, xp = tid & 63;
    float s = 0.f;
#pragma unroll
    for (int dr = 0; dr < 3; ++dr)
#pragma unroll
      for (int dc = 0; dc < 3; ++dc) s += cs[(ry + dr) * 66 + xp + dc];
    invp[tid] = 1.0f / (sqrtf(fmaxf(s, 0.f)) + 1e-8f);
  }
  __syncthreads();

  const int lane = tid & 63;
  const int wid = tid >> 6;
  const int wave_m = wid & 1;
  const int wave_n = wid >> 1;
  const int lane16 = lane & 15;
  const int klane = lane >> 4;
  const int o_base = wave_n * 64;

  f32x4 acc[4][4];
#pragma unroll
  for (int i = 0; i < 4; ++i)
#pragma unroll
    for (int j = 0; j < 4; ++j) acc[i][j] = (f32x4){0.f, 0.f, 0.f, 0.f};
  const ushort* wbase = wt + (o_base + lane16) * 576 + klane * 8;
#pragma unroll
  for (int ks = 0; ks < 18; ++ks) {
    const int t9 = ks >> 1;
    const int kh = t9 / 3, kw = t9 % 3;
    const int cb = (ks & 1) * 64 + klane * 16;
    bf16x8 bfrag[4];
#pragma unroll
    for (int fn = 0; fn < 4; ++fn)
      bfrag[fn] = *(const bf16x8*)(wbase + fn * 16 * 576 + ks * 32);
    const int r4 = wave_m + kh;
#pragma unroll
    for (int fm = 0; fm < 4; ++fm) {
      const int col = fm * 16 + lane16 + kw;
      const int addr = r4 * 8448 + col * 128 + (cb ^ ((col & 7) << 4));
      const bf16x8 afrag = *(const bf16x8*)(xs + addr);
#pragma unroll
      for (int fn = 0; fn < 4; ++fn)
        acc[fm][fn] = __builtin_amdgcn_mfma_f32_16x16x32_bf16(
            afrag, bfrag[fn], acc[fm][fn], 0, 0, 0);
    }
  }
  float ep0[4][4], ep1[4][4];
#pragma unroll
  for (int fm = 0; fm < 4; ++fm) {
    const int m = wave_m * 64 + fm * 16 + klane * 4;
    const f32x4 ip = *(const f32x4*)(invp + m);
#pragma unroll
    for (int fn = 0; fn < 4; ++fn) {
      const f32x4 v = acc[fm][fn];
      const float e0 = __expf(v[0] * ip[0] - 1.f);
      const float e1 = __expf(v[1] * ip[1] - 1.f);
      const float e2 = __expf(v[2] * ip[2] - 1.f);
      const float e3 = __expf(v[3] * ip[3] - 1.f);
      ep0[fm][fn] = e0 + e1;
      ep1[fm][fn] = e2 + e3;
    }
  }
  __syncthreads();
  if (wave_m == 1) {
#pragma unroll
    for (int fm = 0; fm < 4; ++fm) {
      const int ox = fm * 8 + klane * 2;
#pragma unroll
      for (int fn = 0; fn < 4; ++fn) {
        const int o = o_base + fn * 16 + lane16;
        *(float2*)(pool + o * 32 + ox) = make_float2(ep0[fm][fn], ep1[fm][fn]);
      }
    }
  }
  __syncthreads();
  if (wave_m == 0) {
#pragma unroll
    for (int fm = 0; fm < 4; ++fm) {
      const int ox = fm * 8 + klane * 2;
#pragma unroll
      for (int fn = 0; fn < 4; ++fn) {
        const int o = o_base + fn * 16 + lane16;
        const float2 othr = *(const float2*)(pool + o * 32 + ox);
        const float r0 = 0.25f * (ep0[fm][fn] + othr.x);
        const float r1 = 0.25f * (ep1[fm][fn] + othr.y);
        *(float2*)(out + ((((size_t)b * 256 + o) * 32 + y0) * 32 + ox)) =
            make_float2(r0, r1);
      }
    }
  }
}

// ---------------------------------------------------------------------------
extern "C" void kernel_launch(void* const* d_in, const int* in_sizes, int n_in,
                              void* d_out, int out_size, void* d_ws,
                              size_t ws_size, hipStream_t stream) {
  const float* x = (const float*)d_in[0];
  const float* w = (const float*)d_in[1];
  float* out = (float*)d_out;

  const size_t XT_BYTES = 32ull * 64 * 64 * 64 * 2;        // 16,777,216
  const size_t CSS_BYTES = 32ull * 64 * 64 * 4;            //    524,288
  const size_t NEED = XT_BYTES + 2 * CSS_BYTES + 294912;   // 18,120,704

  if (ws_size >= NEED) {
    ushort* xt = (ushort*)d_ws;
    float* css = (float*)((char*)d_ws + XT_BYTES);
    float* invp = (float*)((char*)d_ws + XT_BYTES + CSS_BYTES);
    ushort* wt = (ushort*)((char*)d_ws + XT_BYTES + 2 * CSS_BYTES);

    wnorm_kernel<<<dim3(256), dim3(64), 0, stream>>>(w, wt);
    xprep_kernel<<<dim3(64, 32), dim3(256), 0, stream>>>(x, xt, css);
    invp_kernel<<<dim3(64, 32), dim3(64), 0, stream>>>(css, invp);
    ckn_main<<<dim3(32, 32), dim3(512), 0, stream>>>(xt, invp, wt, out);
  } else {
    ushort* wt = (ushort*)d_ws;
    wnorm_kernel<<<dim3(256), dim3(64), 0, stream>>>(w, wt);
    ckn_main_v1<<<dim3(32, 32), dim3(512), 0, stream>>>(x, wt, out);
  }
}

// Round 3
// 103.712 us; speedup vs baseline: 5.2934x; 5.2934x over previous
//
#include <hip/hip_runtime.h>
#include <hip/hip_bf16.h>

typedef __attribute__((ext_vector_type(8))) short bf16x8;
typedef __attribute__((ext_vector_type(4))) float f32x4;
typedef __attribute__((ext_vector_type(4))) unsigned u32x4;

__device__ __forceinline__ unsigned bfbits(float v) {
  __hip_bfloat16 h = __float2bfloat16(v);
  return (unsigned)*reinterpret_cast<unsigned short*>(&h);
}

// ---------------------------------------------------------------------------
// Kernel 1: normalize weight rows (exact fp32), write bf16, K reordered to
// (kh*3+kw)*64 + c so that c (64 wide) is the contiguous MFMA-K inner dim.
// ---------------------------------------------------------------------------
__global__ void wnorm_kernel(const float* __restrict__ w,
                             ushort* __restrict__ wt) {
  const int o = blockIdx.x;    // 0..255
  const int c = threadIdx.x;   // 0..63
  float v[9];
  float ss = 0.f;
  const float* row = w + o * 576 + c * 9;
#pragma unroll
  for (int j = 0; j < 9; ++j) { v[j] = row[j]; ss += v[j] * v[j]; }
#pragma unroll
  for (int off = 32; off > 0; off >>= 1) ss += __shfl_xor(ss, off);
  const float inv = 1.0f / fmaxf(sqrtf(ss), 1e-12f);
#pragma unroll
  for (int j = 0; j < 9; ++j)
    wt[o * 576 + j * 64 + c] = (ushort)bfbits(v[j] * inv);
}

// ---------------------------------------------------------------------------
// Kernel 2: transpose+convert x [B][C][H][W] fp32 -> xt [B][H][W][C] bf16,
// and css[B][H][W] = sum_c x^2 (fp32, exact). One block per (y, b).
// ---------------------------------------------------------------------------
__global__ __launch_bounds__(256, 8) void xprep_kernel(
    const float* __restrict__ x, ushort* __restrict__ xt,
    float* __restrict__ css) {
  __shared__ __align__(16) unsigned tile[64 * 33];  // [x][c2] padded stride 33
  __shared__ __align__(16) float cssp[4 * 64];
  const int t = threadIdx.x;
  const int y = blockIdx.x, b = blockIdx.y;
  const int c = t >> 2, m = t & 3;
  const int lane = t & 63, w = t >> 6;

  // load 16 floats of row (b,c,y): x-positions px(j) = (j>>2)*16 + m*4 + (j&3)
  const float* src = x + (((size_t)b * 64 + c) * 64 + y) * 64 + m * 4;
  float f[16];
#pragma unroll
  for (int j4 = 0; j4 < 4; ++j4) {
    const f32x4 v = *(const f32x4*)(src + j4 * 16);
#pragma unroll
    for (int k = 0; k < 4; ++k) f[j4 * 4 + k] = v[k];
  }
  // sum of squares over c: lanes stride 4 (16 c per wave), then across 4 waves
  float s[16];
#pragma unroll
  for (int j = 0; j < 16; ++j) {
    float v = f[j] * f[j];
    v += __shfl_xor(v, 4);
    v += __shfl_xor(v, 8);
    v += __shfl_xor(v, 16);
    v += __shfl_xor(v, 32);
    s[j] = v;
  }
  if (lane < 4) {
#pragma unroll
    for (int j4 = 0; j4 < 4; ++j4) {
      f32x4 v = {s[j4 * 4], s[j4 * 4 + 1], s[j4 * 4 + 2], s[j4 * 4 + 3]};
      *(f32x4*)(cssp + w * 64 + j4 * 16 + lane * 4) = v;
    }
  }
  // pack (c even, c odd) bf16 pairs via lane exchange, write transposed tile
  const int parity = c & 1;
  const int c2 = c >> 1;
#pragma unroll
  for (int j = 0; j < 16; ++j) {
    const float pf = __shfl_xor(f[j], 4);  // partner c^1, same x
    const bool mine = parity ? (j >= 8) : (j < 8);
    if (mine) {
      const unsigned dw = parity ? (bfbits(pf) | (bfbits(f[j]) << 16))
                                 : (bfbits(f[j]) | (bfbits(pf) << 16));
      const int px = (j >> 2) * 16 + m * 4 + (j & 3);
      tile[px * 33 + c2] = dw;
    }
  }
  __syncthreads();
  // read back x-major (c contiguous) and store xt coalesced
  {
    const int xr = t >> 2, q = t & 3;
    unsigned d[8];
#pragma unroll
    for (int i = 0; i < 8; ++i) d[i] = tile[xr * 33 + q * 8 + i];
    ushort* dst = xt + (((size_t)b * 64 + y) * 64 + xr) * 64 + q * 16;
    u32x4 v0 = {d[0], d[1], d[2], d[3]};
    u32x4 v1 = {d[4], d[5], d[6], d[7]};
    *(u32x4*)dst = v0;
    *(u32x4*)(dst + 8) = v1;
  }
  if (t < 64) {
    const float sum = cssp[t] + cssp[64 + t] + cssp[128 + t] + cssp[192 + t];
    css[((size_t)b * 64 + y) * 64 + t] = sum;
  }
}

// ---------------------------------------------------------------------------
// Kernel 3: invp[b][y][x] = 1/(sqrt(3x3 window sum of css)+1e-8)
// ---------------------------------------------------------------------------
__global__ void invp_kernel(const float* __restrict__ css,
                            float* __restrict__ invp) {
  const int xx = threadIdx.x;  // 0..63
  const int y = blockIdx.x, b = blockIdx.y;
  float s = 0.f;
#pragma unroll
  for (int dy = -1; dy <= 1; ++dy) {
    const int yy = y + dy;
    if ((unsigned)yy < 64u) s += css[((size_t)b * 64 + yy) * 64 + xx];
  }
  const float sl = __shfl_up(s, 1);
  const float sr = __shfl_down(s, 1);
  const float tot = s + ((xx > 0) ? sl : 0.f) + ((xx < 63) ? sr : 0.f);
  invp[((size_t)b * 64 + y) * 64 + xx] =
      1.0f / (sqrtf(fmaxf(tot, 0.f)) + 1e-8f);
}

// ---------------------------------------------------------------------------
// Main kernel: one block per (image b, output row-pair y0). Stages bf16 rows
// from xt via global_load_lds (pre-swizzled source, linear LDS dest), MFMA
// GEMM M=128 x N=256 x K=576, exp epilogue, 2x2 pool, coalesced store.
//
// __launch_bounds__(512, 4): 4 waves/EU -> 128-VGPR cap. (512, 8) caps at 64
// VGPRs and spills the 64-VGPR accumulator to scratch (round-2 regression:
// 780 MB scratch fetch, MfmaUtil 2.9%).
//
// LDS: xs [4][66][128B] swizzled (byte ^= (col&7)<<4) at [0,33792)
//      pool float[256][36] aliases [0,36864)
//      invp float[128] at [36864,37376)
// ---------------------------------------------------------------------------
__global__ __launch_bounds__(512, 4) void ckn_main(
    const ushort* __restrict__ xt, const float* __restrict__ invp_g,
    const ushort* __restrict__ wt, float* __restrict__ out) {
  __shared__ __align__(16) char smem[37376];
  char* const xs = smem;
  float* const pool = (float*)smem;
  float* const invp = (float*)(smem + 36864);

  const int tid = threadIdx.x;
  const int y0 = blockIdx.x;
  const int b = blockIdx.y;

  // pad columns (col 0 and 65, all 4 rows)
  if (tid < 64) {
    const int r4 = tid >> 4, colsel = (tid >> 3) & 1, cblk = tid & 7;
    *(f32x4*)(xs + r4 * 8448 + colsel * 65 * 128 + cblk * 16) =
        (f32x4){0.f, 0.f, 0.f, 0.f};
  }
  if (tid < 128)
    invp[tid] = invp_g[((size_t)b * 64 + 2 * y0 + (tid >> 6)) * 64 + (tid & 63)];

  // stage 4 rows: one 16B global_load_lds per thread per row.
  // LDS dest linear; source address carries the inverse XOR swizzle.
  {
    const int xx = tid >> 3;
    const int c0 = 8 * ((tid & 7) ^ ((xx + 1) & 7));
    const ushort* srcb = xt + ((size_t)b * 64) * 4096 + (size_t)xx * 64 + c0;
#pragma unroll
    for (int r4 = 0; r4 < 4; ++r4) {
      const int y_img = 2 * y0 - 1 + r4;
      char* dst = xs + r4 * 8448 + 128 + tid * 16;
      if ((unsigned)y_img < 64u) {
        const ushort* src = srcb + (size_t)y_img * 4096;
        __builtin_amdgcn_global_load_lds(
            (const __attribute__((address_space(1))) void*)src,
            (__attribute__((address_space(3))) void*)dst, 16, 0, 0);
      } else {
        *(f32x4*)dst = (f32x4){0.f, 0.f, 0.f, 0.f};
      }
    }
  }
  __syncthreads();

  // K-loop GEMM: 8 waves = 2(M) x 4(N), wave tile 64x64
  const int lane = tid & 63;
  const int wid = tid >> 6;
  const int wave_m = wid & 1;
  const int wave_n = wid >> 1;
  const int lane16 = lane & 15;
  const int klane = lane >> 4;
  const int o_base = wave_n * 64;

  f32x4 acc[4][4];
#pragma unroll
  for (int i = 0; i < 4; ++i)
#pragma unroll
    for (int j = 0; j < 4; ++j) acc[i][j] = (f32x4){0.f, 0.f, 0.f, 0.f};

  const ushort* wbase = wt + (o_base + lane16) * 576 + klane * 8;

#pragma unroll
  for (int ks = 0; ks < 18; ++ks) {
    const int t9 = ks >> 1;
    const int kh = t9 / 3, kw = t9 % 3;
    const int cb = (ks & 1) * 64 + klane * 16;
    bf16x8 bfrag[4];
#pragma unroll
    for (int fn = 0; fn < 4; ++fn)
      bfrag[fn] = *(const bf16x8*)(wbase + fn * 16 * 576 + ks * 32);
    const int r4 = wave_m + kh;
#pragma unroll
    for (int fm = 0; fm < 4; ++fm) {
      const int col = fm * 16 + lane16 + kw;
      const int addr = r4 * 8448 + col * 128 + (cb ^ ((col & 7) << 4));
      const bf16x8 afrag = *(const bf16x8*)(xs + addr);
#pragma unroll
      for (int fn = 0; fn < 4; ++fn)
        acc[fm][fn] = __builtin_amdgcn_mfma_f32_16x16x32_bf16(
            afrag, bfrag[fn], acc[fm][fn], 0, 0, 0);
    }
  }

  // epilogue: exp(cos-1), x-pool in-register
  float ep0[4][4], ep1[4][4];
#pragma unroll
  for (int fm = 0; fm < 4; ++fm) {
    const int mrow = wave_m * 64 + fm * 16 + klane * 4;
    const f32x4 ip = *(const f32x4*)(invp + mrow);
#pragma unroll
    for (int fn = 0; fn < 4; ++fn) {
      const f32x4 v = acc[fm][fn];
      const float e0 = __expf(v[0] * ip[0] - 1.f);
      const float e1 = __expf(v[1] * ip[1] - 1.f);
      const float e2 = __expf(v[2] * ip[2] - 1.f);
      const float e3 = __expf(v[3] * ip[3] - 1.f);
      ep0[fm][fn] = e0 + e1;
      ep1[fm][fn] = e2 + e3;
    }
  }
  __syncthreads();  // xs reads done; pool may alias

  if (wave_m == 1) {
#pragma unroll
    for (int fm = 0; fm < 4; ++fm) {
      const int ox = fm * 8 + klane * 2;
#pragma unroll
      for (int fn = 0; fn < 4; ++fn) {
        const int o = o_base + fn * 16 + lane16;
        *(float2*)(pool + o * 36 + ox) = make_float2(ep0[fm][fn], ep1[fm][fn]);
      }
    }
  }
  __syncthreads();
  if (wave_m == 0) {
#pragma unroll
    for (int fm = 0; fm < 4; ++fm) {
      const int ox = fm * 8 + klane * 2;
#pragma unroll
      for (int fn = 0; fn < 4; ++fn) {
        const int o = o_base + fn * 16 + lane16;
        float2* p = (float2*)(pool + o * 36 + ox);
        const float2 othr = *p;
        *p = make_float2(0.25f * (ep0[fm][fn] + othr.x),
                         0.25f * (ep1[fm][fn] + othr.y));
      }
    }
  }
  __syncthreads();

  // coalesced store: 8 lanes cover one o-row's full 128B
  const size_t obase = (((size_t)b * 256) * 32 + y0) * 32;
#pragma unroll
  for (int j = 0; j < 4; ++j) {
    const int o = j * 64 + (tid >> 3);
    const int ch = (tid & 7) * 4;
    const f32x4 v = *(const f32x4*)(pool + o * 36 + ch);
    *(f32x4*)(out + obase + (size_t)o * 1024 + ch) = v;
  }
}

// ---------------------------------------------------------------------------
// Fallback (round-1 kernel, fused transpose in-block) if ws is too small.
// ---------------------------------------------------------------------------
__global__ __launch_bounds__(512, 4) void ckn_main_v1(
    const float* __restrict__ x, const ushort* __restrict__ wt,
    float* __restrict__ out) {
  __shared__ __align__(16) char smem[43552];
  char* const xs = smem;
  float* const invp = (float*)(smem + 33792);
  float* const cs = (float*)(smem + 34304);
  float* const csp = (float*)(smem + 35360);
  float* const pool = (float*)smem;

  const int tid = threadIdx.x;
  const int y0 = blockIdx.x;
  const int b = blockIdx.y;

  if (tid < 64) {
    const int r4 = tid >> 4, colsel = (tid >> 3) & 1, cblk = tid & 7;
    const int col = colsel * 65;
    *(f32x4*)(xs + r4 * 8448 + col * 128 + cblk * 16) =
        (f32x4){0.f, 0.f, 0.f, 0.f};
  }
  {
    const int xx = tid & 63;
    const int cg = tid >> 6;
    const int col = xx + 1;
    const int sw = (cg * 16) ^ ((col & 7) << 4);
#pragma unroll
    for (int r4 = 0; r4 < 4; ++r4) {
      const int y_img = 2 * y0 - 1 + r4;
      char* dst = xs + r4 * 8448 + col * 128 + sw;
      if ((unsigned)y_img < 64u) {
        const float* src =
            x + (((size_t)b * 64 + cg * 8) * 64 + y_img) * 64 + xx;
        float ss = 0.f;
        union { bf16x8 v; ushort u[8]; } pk;
#pragma unroll
        for (int j = 0; j < 8; ++j) {
          const float f = src[(size_t)j * 4096];
          ss += f * f;
          pk.u[j] = (ushort)bfbits(f);
        }
        *(bf16x8*)dst = pk.v;
        csp[(r4 * 8 + cg) * 64 + xx] = ss;
      } else {
        *(bf16x8*)dst = (bf16x8){0, 0, 0, 0, 0, 0, 0, 0};
        csp[(r4 * 8 + cg) * 64 + xx] = 0.f;
      }
    }
  }
  __syncthreads();
  if (tid < 256) {
    const int r4 = tid >> 6, xc = tid & 63;
    float s = 0.f;
#pragma unroll
    for (int cg = 0; cg < 8; ++cg) s += csp[(r4 * 8 + cg) * 64 + xc];
    cs[r4 * 66 + xc + 1] = s;
  }
  if (tid >= 256 && tid < 264) {
    const int t = tid - 256;
    cs[(t >> 1) * 66 + (t & 1) * 65] = 0.f;
  }
  __syncthreads();
  if (tid < 128) {
    const int ry = tid >> 6, xp = tid & 63;
    float s = 0.f;
#pragma unroll
    for (int dr = 0; dr < 3; ++dr)
#pragma unroll
      for (int dc = 0; dc < 3; ++dc) s += cs[(ry + dr) * 66 + xp + dc];
    invp[tid] = 1.0f / (sqrtf(fmaxf(s, 0.f)) + 1e-8f);
  }
  __syncthreads();

  const int lane = tid & 63;
  const int wid = tid >> 6;
  const int wave_m = wid & 1;
  const int wave_n = wid >> 1;
  const int lane16 = lane & 15;
  const int klane = lane >> 4;
  const int o_base = wave_n * 64;

  f32x4 acc[4][4];
#pragma unroll
  for (int i = 0; i < 4; ++i)
#pragma unroll
    for (int j = 0; j < 4; ++j) acc[i][j] = (f32x4){0.f, 0.f, 0.f, 0.f};
  const ushort* wbase = wt + (o_base + lane16) * 576 + klane * 8;
#pragma unroll
  for (int ks = 0; ks < 18; ++ks) {
    const int t9 = ks >> 1;
    const int kh = t9 / 3, kw = t9 % 3;
    const int cb = (ks & 1) * 64 + klane * 16;
    bf16x8 bfrag[4];
#pragma unroll
    for (int fn = 0; fn < 4; ++fn)
      bfrag[fn] = *(const bf16x8*)(wbase + fn * 16 * 576 + ks * 32);
    const int r4 = wave_m + kh;
#pragma unroll
    for (int fm = 0; fm < 4; ++fm) {
      const int col = fm * 16 + lane16 + kw;
      const int addr = r4 * 8448 + col * 128 + (cb ^ ((col & 7) << 4));
      const bf16x8 afrag = *(const bf16x8*)(xs + addr);
#pragma unroll
      for (int fn = 0; fn < 4; ++fn)
        acc[fm][fn] = __builtin_amdgcn_mfma_f32_16x16x32_bf16(
            afrag, bfrag[fn], acc[fm][fn], 0, 0, 0);
    }
  }
  float ep0[4][4], ep1[4][4];
#pragma unroll
  for (int fm = 0; fm < 4; ++fm) {
    const int m = wave_m * 64 + fm * 16 + klane * 4;
    const f32x4 ip = *(const f32x4*)(invp + m);
#pragma unroll
    for (int fn = 0; fn < 4; ++fn) {
      const f32x4 v = acc[fm][fn];
      const float e0 = __expf(v[0] * ip[0] - 1.f);
      const float e1 = __expf(v[1] * ip[1] - 1.f);
      const float e2 = __expf(v[2] * ip[2] - 1.f);
      const float e3 = __expf(v[3] * ip[3] - 1.f);
      ep0[fm][fn] = e0 + e1;
      ep1[fm][fn] = e2 + e3;
    }
  }
  __syncthreads();
  if (wave_m == 1) {
#pragma unroll
    for (int fm = 0; fm < 4; ++fm) {
      const int ox = fm * 8 + klane * 2;
#pragma unroll
      for (int fn = 0; fn < 4; ++fn) {
        const int o = o_base + fn * 16 + lane16;
        *(float2*)(pool + o * 32 + ox) = make_float2(ep0[fm][fn], ep1[fm][fn]);
      }
    }
  }
  __syncthreads();
  if (wave_m == 0) {
#pragma unroll
    for (int fm = 0; fm < 4; ++fm) {
      const int ox = fm * 8 + klane * 2;
#pragma unroll
      for (int fn = 0; fn < 4; ++fn) {
        const int o = o_base + fn * 16 + lane16;
        const float2 othr = *(const float2*)(pool + o * 32 + ox);
        const float r0 = 0.25f * (ep0[fm][fn] + othr.x);
        const float r1 = 0.25f * (ep1[fm][fn] + othr.y);
        *(float2*)(out + ((((size_t)b * 256 + o) * 32 + y0) * 32 + ox)) =
            make_float2(r0, r1);
      }
    }
  }
}

// ---------------------------------------------------------------------------
extern "C" void kernel_launch(void* const* d_in, const int* in_sizes, int n_in,
                              void* d_out, int out_size, void* d_ws,
                              size_t ws_size, hipStream_t stream) {
  const float* x = (const float*)d_in[0];
  const float* w = (const float*)d_in[1];
  float* out = (float*)d_out;

  const size_t XT_BYTES = 32ull * 64 * 64 * 64 * 2;        // 16,777,216
  const size_t CSS_BYTES = 32ull * 64 * 64 * 4;            //    524,288
  const size_t NEED = XT_BYTES + 2 * CSS_BYTES + 294912;   // 18,120,704

  if (ws_size >= NEED) {
    ushort* xt = (ushort*)d_ws;
    float* css = (float*)((char*)d_ws + XT_BYTES);
    float* invp = (float*)((char*)d_ws + XT_BYTES + CSS_BYTES);
    ushort* wt = (ushort*)((char*)d_ws + XT_BYTES + 2 * CSS_BYTES);

    wnorm_kernel<<<dim3(256), dim3(64), 0, stream>>>(w, wt);
    xprep_kernel<<<dim3(64, 32), dim3(256), 0, stream>>>(x, xt, css);
    invp_kernel<<<dim3(64, 32), dim3(64), 0, stream>>>(css, invp);
    ckn_main<<<dim3(32, 32), dim3(512), 0, stream>>>(xt, invp, wt, out);
  } else {
    ushort* wt = (ushort*)d_ws;
    wnorm_kernel<<<dim3(256), dim3(64), 0, stream>>>(w, wt);
    ckn_main_v1<<<dim3(32, 32), dim3(512), 0, stream>>>(x, wt, out);
  }
}

// Round 4
// 85.093 us; speedup vs baseline: 6.4516x; 1.2188x over previous
//
#include <hip/hip_runtime.h>
#include <hip/hip_bf16.h>

typedef __attribute__((ext_vector_type(8))) short bf16x8;
typedef __attribute__((ext_vector_type(4))) float f32x4;
typedef __attribute__((ext_vector_type(4))) unsigned u32x4;

__device__ __forceinline__ unsigned bfbits(float v) {
  __hip_bfloat16 h = __float2bfloat16(v);
  return (unsigned)*reinterpret_cast<unsigned short*>(&h);
}

// ---------------------------------------------------------------------------
// Kernel 1: normalize weight rows (exact fp32), write bf16 in TWO layouts:
//  wt  [o][ (kh*3+kw)*64 + c ]                      (legacy, for fallback)
//  wt2 [ks][g=o/16][r=o%16][kq*8+e]  (k = ks*32+kq*8+e)  -- coalesced bfrag
// ---------------------------------------------------------------------------
__global__ void wnorm_kernel(const float* __restrict__ w,
                             ushort* __restrict__ wt,
                             ushort* __restrict__ wt2) {
  const int o = blockIdx.x;    // 0..255
  const int c = threadIdx.x;   // 0..63
  float v[9];
  float ss = 0.f;
  const float* row = w + o * 576 + c * 9;
#pragma unroll
  for (int j = 0; j < 9; ++j) { v[j] = row[j]; ss += v[j] * v[j]; }
#pragma unroll
  for (int off = 32; off > 0; off >>= 1) ss += __shfl_xor(ss, off);
  const float inv = 1.0f / fmaxf(sqrtf(ss), 1e-12f);
  const int g = o >> 4, r = o & 15;
  const int kq = (c >> 3) & 3, e = c & 7;
#pragma unroll
  for (int j = 0; j < 9; ++j) {
    const ushort bv = (ushort)bfbits(v[j] * inv);
    wt[o * 576 + j * 64 + c] = bv;
    const int ks = j * 2 + (c >> 5);
    wt2[((ks * 16 + g) * 16 + r) * 32 + kq * 8 + e] = bv;
  }
}

// ---------------------------------------------------------------------------
// Kernel 2: transpose+convert x [B][C][H][W] fp32 -> xt [B][H][W][C] bf16,
// and css[B][H][W] = sum_c x^2 (fp32, exact). One block per (y, b).
// ---------------------------------------------------------------------------
__global__ __launch_bounds__(256, 8) void xprep_kernel(
    const float* __restrict__ x, ushort* __restrict__ xt,
    float* __restrict__ css) {
  __shared__ __align__(16) unsigned tile[64 * 33];  // [x][c2] padded stride 33
  __shared__ __align__(16) float cssp[4 * 64];
  const int t = threadIdx.x;
  const int y = blockIdx.x, b = blockIdx.y;
  const int c = t >> 2, m = t & 3;
  const int lane = t & 63, w = t >> 6;

  const float* src = x + (((size_t)b * 64 + c) * 64 + y) * 64 + m * 4;
  float f[16];
#pragma unroll
  for (int j4 = 0; j4 < 4; ++j4) {
    const f32x4 v = *(const f32x4*)(src + j4 * 16);
#pragma unroll
    for (int k = 0; k < 4; ++k) f[j4 * 4 + k] = v[k];
  }
  float s[16];
#pragma unroll
  for (int j = 0; j < 16; ++j) {
    float v = f[j] * f[j];
    v += __shfl_xor(v, 4);
    v += __shfl_xor(v, 8);
    v += __shfl_xor(v, 16);
    v += __shfl_xor(v, 32);
    s[j] = v;
  }
  if (lane < 4) {
#pragma unroll
    for (int j4 = 0; j4 < 4; ++j4) {
      f32x4 v = {s[j4 * 4], s[j4 * 4 + 1], s[j4 * 4 + 2], s[j4 * 4 + 3]};
      *(f32x4*)(cssp + w * 64 + j4 * 16 + lane * 4) = v;
    }
  }
  const int parity = c & 1;
  const int c2 = c >> 1;
#pragma unroll
  for (int j = 0; j < 16; ++j) {
    const float pf = __shfl_xor(f[j], 4);
    const bool mine = parity ? (j >= 8) : (j < 8);
    if (mine) {
      const unsigned dw = parity ? (bfbits(pf) | (bfbits(f[j]) << 16))
                                 : (bfbits(f[j]) | (bfbits(pf) << 16));
      const int px = (j >> 2) * 16 + m * 4 + (j & 3);
      tile[px * 33 + c2] = dw;
    }
  }
  __syncthreads();
  {
    const int xr = t >> 2, q = t & 3;
    unsigned d[8];
#pragma unroll
    for (int i = 0; i < 8; ++i) d[i] = tile[xr * 33 + q * 8 + i];
    ushort* dst = xt + (((size_t)b * 64 + y) * 64 + xr) * 64 + q * 16;
    u32x4 v0 = {d[0], d[1], d[2], d[3]};
    u32x4 v1 = {d[4], d[5], d[6], d[7]};
    *(u32x4*)dst = v0;
    *(u32x4*)(dst + 8) = v1;
  }
  if (t < 64) {
    const float sum = cssp[t] + cssp[64 + t] + cssp[128 + t] + cssp[192 + t];
    css[((size_t)b * 64 + y) * 64 + t] = sum;
  }
}

// ---------------------------------------------------------------------------
// Kernel 3: invp[b][y][x] = 1/(sqrt(3x3 window sum of css)+1e-8)
// ---------------------------------------------------------------------------
__global__ void invp_kernel(const float* __restrict__ css,
                            float* __restrict__ invp) {
  const int xx = threadIdx.x;  // 0..63
  const int y = blockIdx.x, b = blockIdx.y;
  float s = 0.f;
#pragma unroll
  for (int dy = -1; dy <= 1; ++dy) {
    const int yy = y + dy;
    if ((unsigned)yy < 64u) s += css[((size_t)b * 64 + yy) * 64 + xx];
  }
  const float sl = __shfl_up(s, 1);
  const float sr = __shfl_down(s, 1);
  const float tot = s + ((xx > 0) ? sl : 0.f) + ((xx < 63) ? sr : 0.f);
  invp[((size_t)b * 64 + y) * 64 + xx] =
      1.0f / (sqrtf(fmaxf(tot, 0.f)) + 1e-8f);
}

// ---------------------------------------------------------------------------
// Main kernel: one block per (image b, output row-pair y0). A staged in LDS
// (global_load_lds, pre-swizzled source); B read from wt2 (coalesced 1KB/wave
// per fragment) with depth-2 register prefetch; MFMA GEMM M=128 x N=256 x
// K=576; exp epilogue; 2x2 pool; coalesced store.
//
// __launch_bounds__(512, 4): 128-reg cap (acc 64 AGPR + ~56 VGPR). (512,8)
// spills (round-2 regression).
//
// LDS: xs [4][66][128B] swizzled (byte ^= (col&7)<<4) at [0,33792)
//      pool float[256][36] aliases [0,36864)
//      invp float[128] at [36864,37376)
// ---------------------------------------------------------------------------
__global__ __launch_bounds__(512, 4) void ckn_main(
    const ushort* __restrict__ xt, const float* __restrict__ invp_g,
    const ushort* __restrict__ wt2, float* __restrict__ out) {
  __shared__ __align__(16) char smem[37376];
  char* const xs = smem;
  float* const pool = (float*)smem;
  float* const invp = (float*)(smem + 36864);

  const int tid = threadIdx.x;
  const int y0 = blockIdx.x;
  const int b = blockIdx.y;

  // pad columns (col 0 and 65, all 4 rows)
  if (tid < 64) {
    const int r4 = tid >> 4, colsel = (tid >> 3) & 1, cblk = tid & 7;
    *(f32x4*)(xs + r4 * 8448 + colsel * 65 * 128 + cblk * 16) =
        (f32x4){0.f, 0.f, 0.f, 0.f};
  }
  if (tid < 128)
    invp[tid] = invp_g[((size_t)b * 64 + 2 * y0 + (tid >> 6)) * 64 + (tid & 63)];

  // stage 4 rows: one 16B global_load_lds per thread per row.
  {
    const int xx = tid >> 3;
    const int c0 = 8 * ((tid & 7) ^ ((xx + 1) & 7));
    const ushort* srcb = xt + ((size_t)b * 64) * 4096 + (size_t)xx * 64 + c0;
#pragma unroll
    for (int r4 = 0; r4 < 4; ++r4) {
      const int y_img = 2 * y0 - 1 + r4;
      char* dst = xs + r4 * 8448 + 128 + tid * 16;
      if ((unsigned)y_img < 64u) {
        const ushort* src = srcb + (size_t)y_img * 4096;
        __builtin_amdgcn_global_load_lds(
            (const __attribute__((address_space(1))) void*)src,
            (__attribute__((address_space(3))) void*)dst, 16, 0, 0);
      } else {
        *(f32x4*)dst = (f32x4){0.f, 0.f, 0.f, 0.f};
      }
    }
  }

  const int lane = tid & 63;
  const int wid = tid >> 6;
  const int wave_m = wid & 1;
  const int wave_n = wid >> 1;
  const int lane16 = lane & 15;
  const int klane = lane >> 4;
  const int o_base = wave_n * 64;

  // B base in wt2 (ushort elements): (ks,fn) fragment at +ks*8192 + fn*512.
  const ushort* wb2 = wt2 + (size_t)(wave_n * 4) * 512 + lane16 * 32 + klane * 8;

  // depth-2 B prefetch: issue ks=0,1 BEFORE the barrier (overlaps staging DMA)
  bf16x8 bq[2][4];
#pragma unroll
  for (int fn = 0; fn < 4; ++fn) bq[0][fn] = *(const bf16x8*)(wb2 + fn * 512);
#pragma unroll
  for (int fn = 0; fn < 4; ++fn)
    bq[1][fn] = *(const bf16x8*)(wb2 + 8192 + fn * 512);

  __syncthreads();

  f32x4 acc[4][4];
#pragma unroll
  for (int i = 0; i < 4; ++i)
#pragma unroll
    for (int j = 0; j < 4; ++j) acc[i][j] = (f32x4){0.f, 0.f, 0.f, 0.f};

#pragma unroll
  for (int ks = 0; ks < 18; ++ks) {
    const int t9 = ks >> 1;
    const int kh = t9 / 3, kw = t9 % 3;
    const int cb = (ks & 1) * 64 + klane * 16;
    const int r4 = wave_m + kh;
    const int cur = ks & 1;
#pragma unroll
    for (int fm = 0; fm < 4; ++fm) {
      const int col = fm * 16 + lane16 + kw;
      const int addr = r4 * 8448 + col * 128 + (cb ^ ((col & 7) << 4));
      const bf16x8 afrag = *(const bf16x8*)(xs + addr);
#pragma unroll
      for (int fn = 0; fn < 4; ++fn)
        acc[fm][fn] = __builtin_amdgcn_mfma_f32_16x16x32_bf16(
            afrag, bq[cur][fn], acc[fm][fn], 0, 0, 0);
    }
    if (ks + 2 < 18) {
#pragma unroll
      for (int fn = 0; fn < 4; ++fn)
        bq[cur][fn] = *(const bf16x8*)(wb2 + (ks + 2) * 8192 + fn * 512);
    }
  }

  // epilogue: exp(cos-1), x-pool in-register
  float ep0[4][4], ep1[4][4];
#pragma unroll
  for (int fm = 0; fm < 4; ++fm) {
    const int mrow = wave_m * 64 + fm * 16 + klane * 4;
    const f32x4 ip = *(const f32x4*)(invp + mrow);
#pragma unroll
    for (int fn = 0; fn < 4; ++fn) {
      const f32x4 v = acc[fm][fn];
      const float e0 = __expf(v[0] * ip[0] - 1.f);
      const float e1 = __expf(v[1] * ip[1] - 1.f);
      const float e2 = __expf(v[2] * ip[2] - 1.f);
      const float e3 = __expf(v[3] * ip[3] - 1.f);
      ep0[fm][fn] = e0 + e1;
      ep1[fm][fn] = e2 + e3;
    }
  }
  __syncthreads();  // xs reads done; pool may alias

  if (wave_m == 1) {
#pragma unroll
    for (int fm = 0; fm < 4; ++fm) {
      const int ox = fm * 8 + klane * 2;
#pragma unroll
      for (int fn = 0; fn < 4; ++fn) {
        const int o = o_base + fn * 16 + lane16;
        *(float2*)(pool + o * 36 + ox) = make_float2(ep0[fm][fn], ep1[fm][fn]);
      }
    }
  }
  __syncthreads();
  if (wave_m == 0) {
#pragma unroll
    for (int fm = 0; fm < 4; ++fm) {
      const int ox = fm * 8 + klane * 2;
#pragma unroll
      for (int fn = 0; fn < 4; ++fn) {
        const int o = o_base + fn * 16 + lane16;
        float2* p = (float2*)(pool + o * 36 + ox);
        const float2 othr = *p;
        *p = make_float2(0.25f * (ep0[fm][fn] + othr.x),
                         0.25f * (ep1[fm][fn] + othr.y));
      }
    }
  }
  __syncthreads();

  // coalesced store: 8 lanes cover one o-row's full 128B
  const size_t obase = (((size_t)b * 256) * 32 + y0) * 32;
#pragma unroll
  for (int j = 0; j < 4; ++j) {
    const int o = j * 64 + (tid >> 3);
    const int ch = (tid & 7) * 4;
    const f32x4 v = *(const f32x4*)(pool + o * 36 + ch);
    *(f32x4*)(out + obase + (size_t)o * 1024 + ch) = v;
  }
}

// ---------------------------------------------------------------------------
// Fallback (round-1 kernel, fused transpose in-block) if ws is too small.
// ---------------------------------------------------------------------------
__global__ __launch_bounds__(512, 4) void ckn_main_v1(
    const float* __restrict__ x, const ushort* __restrict__ wt,
    float* __restrict__ out) {
  __shared__ __align__(16) char smem[43552];
  char* const xs = smem;
  float* const invp = (float*)(smem + 33792);
  float* const cs = (float*)(smem + 34304);
  float* const csp = (float*)(smem + 35360);
  float* const pool = (float*)smem;

  const int tid = threadIdx.x;
  const int y0 = blockIdx.x;
  const int b = blockIdx.y;

  if (tid < 64) {
    const int r4 = tid >> 4, colsel = (tid >> 3) & 1, cblk = tid & 7;
    const int col = colsel * 65;
    *(f32x4*)(xs + r4 * 8448 + col * 128 + cblk * 16) =
        (f32x4){0.f, 0.f, 0.f, 0.f};
  }
  {
    const int xx = tid & 63;
    const int cg = tid >> 6;
    const int col = xx + 1;
    const int sw = (cg * 16) ^ ((col & 7) << 4);
#pragma unroll
    for (int r4 = 0; r4 < 4; ++r4) {
      const int y_img = 2 * y0 - 1 + r4;
      char* dst = xs + r4 * 8448 + col * 128 + sw;
      if ((unsigned)y_img < 64u) {
        const float* src =
            x + (((size_t)b * 64 + cg * 8) * 64 + y_img) * 64 + xx;
        float ss = 0.f;
        union { bf16x8 v; ushort u[8]; } pk;
#pragma unroll
        for (int j = 0; j < 8; ++j) {
          const float f = src[(size_t)j * 4096];
          ss += f * f;
          pk.u[j] = (ushort)bfbits(f);
        }
        *(bf16x8*)dst = pk.v;
        csp[(r4 * 8 + cg) * 64 + xx] = ss;
      } else {
        *(bf16x8*)dst = (bf16x8){0, 0, 0, 0, 0, 0, 0, 0};
        csp[(r4 * 8 + cg) * 64 + xx] = 0.f;
      }
    }
  }
  __syncthreads();
  if (tid < 256) {
    const int r4 = tid >> 6, xc = tid & 63;
    float s = 0.f;
#pragma unroll
    for (int cg = 0; cg < 8; ++cg) s += csp[(r4 * 8 + cg) * 64 + xc];
    cs[r4 * 66 + xc + 1] = s;
  }
  if (tid >= 256 && tid < 264) {
    const int t = tid - 256;
    cs[(t >> 1) * 66 + (t & 1) * 65] = 0.f;
  }
  __syncthreads();
  if (tid < 128) {
    const int ry = tid >> 6, xp = tid & 63;
    float s = 0.f;
#pragma unroll
    for (int dr = 0; dr < 3; ++dr)
#pragma unroll
      for (int dc = 0; dc < 3; ++dc) s += cs[(ry + dr) * 66 + xp + dc];
    invp[tid] = 1.0f / (sqrtf(fmaxf(s, 0.f)) + 1e-8f);
  }
  __syncthreads();

  const int lane = tid & 63;
  const int wid = tid >> 6;
  const int wave_m = wid & 1;
  const int wave_n = wid >> 1;
  const int lane16 = lane & 15;
  const int klane = lane >> 4;
  const int o_base = wave_n * 64;

  f32x4 acc[4][4];
#pragma unroll
  for (int i = 0; i < 4; ++i)
#pragma unroll
    for (int j = 0; j < 4; ++j) acc[i][j] = (f32x4){0.f, 0.f, 0.f, 0.f};
  const ushort* wbase = wt + (o_base + lane16) * 576 + klane * 8;
#pragma unroll
  for (int ks = 0; ks < 18; ++ks) {
    const int t9 = ks >> 1;
    const int kh = t9 / 3, kw = t9 % 3;
    const int cb = (ks & 1) * 64 + klane * 16;
    bf16x8 bfrag[4];
#pragma unroll
    for (int fn = 0; fn < 4; ++fn)
      bfrag[fn] = *(const bf16x8*)(wbase + fn * 16 * 576 + ks * 32);
    const int r4 = wave_m + kh;
#pragma unroll
    for (int fm = 0; fm < 4; ++fm) {
      const int col = fm * 16 + lane16 + kw;
      const int addr = r4 * 8448 + col * 128 + (cb ^ ((col & 7) << 4));
      const bf16x8 afrag = *(const bf16x8*)(xs + addr);
#pragma unroll
      for (int fn = 0; fn < 4; ++fn)
        acc[fm][fn] = __builtin_amdgcn_mfma_f32_16x16x32_bf16(
            afrag, bfrag[fn], acc[fm][fn], 0, 0, 0);
    }
  }
  float ep0[4][4], ep1[4][4];
#pragma unroll
  for (int fm = 0; fm < 4; ++fm) {
    const int m = wave_m * 64 + fm * 16 + klane * 4;
    const f32x4 ip = *(const f32x4*)(invp + m);
#pragma unroll
    for (int fn = 0; fn < 4; ++fn) {
      const f32x4 v = acc[fm][fn];
      const float e0 = __expf(v[0] * ip[0] - 1.f);
      const float e1 = __expf(v[1] * ip[1] - 1.f);
      const float e2 = __expf(v[2] * ip[2] - 1.f);
      const float e3 = __expf(v[3] * ip[3] - 1.f);
      ep0[fm][fn] = e0 + e1;
      ep1[fm][fn] = e2 + e3;
    }
  }
  __syncthreads();
  if (wave_m == 1) {
#pragma unroll
    for (int fm = 0; fm < 4; ++fm) {
      const int ox = fm * 8 + klane * 2;
#pragma unroll
      for (int fn = 0; fn < 4; ++fn) {
        const int o = o_base + fn * 16 + lane16;
        *(float2*)(pool + o * 32 + ox) = make_float2(ep0[fm][fn], ep1[fm][fn]);
      }
    }
  }
  __syncthreads();
  if (wave_m == 0) {
#pragma unroll
    for (int fm = 0; fm < 4; ++fm) {
      const int ox = fm * 8 + klane * 2;
#pragma unroll
      for (int fn = 0; fn < 4; ++fn) {
        const int o = o_base + fn * 16 + lane16;
        const float2 othr = *(const float2*)(pool + o * 32 + ox);
        const float r0 = 0.25f * (ep0[fm][fn] + othr.x);
        const float r1 = 0.25f * (ep1[fm][fn] + othr.y);
        *(float2*)(out + ((((size_t)b * 256 + o) * 32 + y0) * 32 + ox)) =
            make_float2(r0, r1);
      }
    }
  }
}

// ---------------------------------------------------------------------------
extern "C" void kernel_launch(void* const* d_in, const int* in_sizes, int n_in,
                              void* d_out, int out_size, void* d_ws,
                              size_t ws_size, hipStream_t stream) {
  const float* x = (const float*)d_in[0];
  const float* w = (const float*)d_in[1];
  float* out = (float*)d_out;

  const size_t XT_BYTES = 32ull * 64 * 64 * 64 * 2;   // 16,777,216
  const size_t CSS_BYTES = 32ull * 64 * 64 * 4;       //    524,288
  const size_t WT_BYTES = 256ull * 576 * 2;           //    294,912
  const size_t NEED = XT_BYTES + 2 * CSS_BYTES + 2 * WT_BYTES;

  if (ws_size >= NEED) {
    ushort* xt = (ushort*)d_ws;
    float* css = (float*)((char*)d_ws + XT_BYTES);
    float* invp = (float*)((char*)d_ws + XT_BYTES + CSS_BYTES);
    ushort* wt = (ushort*)((char*)d_ws + XT_BYTES + 2 * CSS_BYTES);
    ushort* wt2 = (ushort*)((char*)d_ws + XT_BYTES + 2 * CSS_BYTES + WT_BYTES);

    wnorm_kernel<<<dim3(256), dim3(64), 0, stream>>>(w, wt, wt2);
    xprep_kernel<<<dim3(64, 32), dim3(256), 0, stream>>>(x, xt, css);
    invp_kernel<<<dim3(64, 32), dim3(64), 0, stream>>>(css, invp);
    ckn_main<<<dim3(32, 32), dim3(512), 0, stream>>>(xt, invp, wt2, out);
  } else {
    // minimal-ws fallback: wt legacy layout + wt2 right after
    ushort* wt = (ushort*)d_ws;
    ushort* wt2 = wt + 256 * 576;
    if (ws_size >= 2 * WT_BYTES) {
      wnorm_kernel<<<dim3(256), dim3(64), 0, stream>>>(w, wt, wt2);
      ckn_main_v1<<<dim3(32, 32), dim3(512), 0, stream>>>(x, wt, out);
    }
  }
}

// Round 5
// 71.392 us; speedup vs baseline: 7.6898x; 1.1919x over previous
//
#include <hip/hip_runtime.h>
#include <hip/hip_bf16.h>

typedef __attribute__((ext_vector_type(8))) short bf16x8;
typedef __attribute__((ext_vector_type(4))) float f32x4;
typedef __attribute__((ext_vector_type(16))) float f32x16;
typedef __attribute__((ext_vector_type(4))) unsigned u32x4;

__device__ __forceinline__ unsigned bfbits(float v) {
  __hip_bfloat16 h = __float2bfloat16(v);
  return (unsigned)*reinterpret_cast<unsigned short*>(&h);
}

// ---------------------------------------------------------------------------
// Kernel 1: normalize weight rows (exact fp32), write bf16 in TWO layouts:
//  wt  [o][ (kh*3+kw)*64 + c ]          (legacy 16x16 layout, for fallback)
//  wt3 [ks][g=o/32][n=o%32][k16]        (32x32x16 fragment-major; k = ks*16+k16,
//                                        global k ordering (kh*3+kw)*64 + c)
// ---------------------------------------------------------------------------
__global__ void wnorm_kernel(const float* __restrict__ w,
                             ushort* __restrict__ wt,
                             ushort* __restrict__ wt3) {
  const int o = blockIdx.x;    // 0..255
  const int c = threadIdx.x;   // 0..63
  float v[9];
  float ss = 0.f;
  const float* row = w + o * 576 + c * 9;
#pragma unroll
  for (int j = 0; j < 9; ++j) { v[j] = row[j]; ss += v[j] * v[j]; }
#pragma unroll
  for (int off = 32; off > 0; off >>= 1) ss += __shfl_xor(ss, off);
  const float inv = 1.0f / fmaxf(sqrtf(ss), 1e-12f);
  const int g = o >> 5, n = o & 31;
#pragma unroll
  for (int j = 0; j < 9; ++j) {
    const ushort bv = (ushort)bfbits(v[j] * inv);
    wt[o * 576 + j * 64 + c] = bv;
    const int ks = j * 4 + (c >> 4);
    wt3[((ks * 8 + g) * 32 + n) * 16 + (c & 15)] = bv;
  }
}

// ---------------------------------------------------------------------------
// Kernel 2: transpose+convert x [B][C][H][W] fp32 -> xt [B][H][W][C] bf16,
// and css[B][H][W] = sum_c x^2 (fp32, exact). One block per (y, b).
// ---------------------------------------------------------------------------
__global__ __launch_bounds__(256, 8) void xprep_kernel(
    const float* __restrict__ x, ushort* __restrict__ xt,
    float* __restrict__ css) {
  __shared__ __align__(16) unsigned tile[64 * 33];  // [x][c2] padded stride 33
  __shared__ __align__(16) float cssp[4 * 64];
  const int t = threadIdx.x;
  const int y = blockIdx.x, b = blockIdx.y;
  const int c = t >> 2, m = t & 3;
  const int lane = t & 63, w = t >> 6;

  const float* src = x + (((size_t)b * 64 + c) * 64 + y) * 64 + m * 4;
  float f[16];
#pragma unroll
  for (int j4 = 0; j4 < 4; ++j4) {
    const f32x4 v = *(const f32x4*)(src + j4 * 16);
#pragma unroll
    for (int k = 0; k < 4; ++k) f[j4 * 4 + k] = v[k];
  }
  float s[16];
#pragma unroll
  for (int j = 0; j < 16; ++j) {
    float v = f[j] * f[j];
    v += __shfl_xor(v, 4);
    v += __shfl_xor(v, 8);
    v += __shfl_xor(v, 16);
    v += __shfl_xor(v, 32);
    s[j] = v;
  }
  if (lane < 4) {
#pragma unroll
    for (int j4 = 0; j4 < 4; ++j4) {
      f32x4 v = {s[j4 * 4], s[j4 * 4 + 1], s[j4 * 4 + 2], s[j4 * 4 + 3]};
      *(f32x4*)(cssp + w * 64 + j4 * 16 + lane * 4) = v;
    }
  }
  const int parity = c & 1;
  const int c2 = c >> 1;
#pragma unroll
  for (int j = 0; j < 16; ++j) {
    const float pf = __shfl_xor(f[j], 4);
    const bool mine = parity ? (j >= 8) : (j < 8);
    if (mine) {
      const unsigned dw = parity ? (bfbits(pf) | (bfbits(f[j]) << 16))
                                 : (bfbits(f[j]) | (bfbits(pf) << 16));
      const int px = (j >> 2) * 16 + m * 4 + (j & 3);
      tile[px * 33 + c2] = dw;
    }
  }
  __syncthreads();
  {
    const int xr = t >> 2, q = t & 3;
    unsigned d[8];
#pragma unroll
    for (int i = 0; i < 8; ++i) d[i] = tile[xr * 33 + q * 8 + i];
    ushort* dst = xt + (((size_t)b * 64 + y) * 64 + xr) * 64 + q * 16;
    u32x4 v0 = {d[0], d[1], d[2], d[3]};
    u32x4 v1 = {d[4], d[5], d[6], d[7]};
    *(u32x4*)dst = v0;
    *(u32x4*)(dst + 8) = v1;
  }
  if (t < 64) {
    const float sum = cssp[t] + cssp[64 + t] + cssp[128 + t] + cssp[192 + t];
    css[((size_t)b * 64 + y) * 64 + t] = sum;
  }
}

// ---------------------------------------------------------------------------
// Kernel 3: invp[b][y][x] = 1/(sqrt(3x3 window sum of css)+1e-8)
// ---------------------------------------------------------------------------
__global__ void invp_kernel(const float* __restrict__ css,
                            float* __restrict__ invp) {
  const int xx = threadIdx.x;  // 0..63
  const int y = blockIdx.x, b = blockIdx.y;
  float s = 0.f;
#pragma unroll
  for (int dy = -1; dy <= 1; ++dy) {
    const int yy = y + dy;
    if ((unsigned)yy < 64u) s += css[((size_t)b * 64 + yy) * 64 + xx];
  }
  const float sl = __shfl_up(s, 1);
  const float sr = __shfl_down(s, 1);
  const float tot = s + ((xx > 0) ? sl : 0.f) + ((xx < 63) ? sr : 0.f);
  invp[((size_t)b * 64 + y) * 64 + xx] =
      1.0f / (sqrtf(fmaxf(tot, 0.f)) + 1e-8f);
}

// ---------------------------------------------------------------------------
// Main kernel: one block per (image b, output row-pair y0). A staged in LDS
// (global_load_lds, pre-swizzled source); B from wt3 (contiguous 1KB/wave per
// fragment, depth-2 register prefetch); 32x32x16 MFMA GEMM (M=128 x N=256 x
// K=576, 36 K-steps x {2 A ds_read_b128, 2 B loads, 4 MFMA}); exp epilogue;
// 2x2 pool; coalesced store.
//
// __launch_bounds__(512, 4): 128-reg cap (acc 64 AGPR + ~55 VGPR).
//
// LDS: xs [4][66][128B] swizzled (byte ^= (col&7)<<4) at [0,33792)
//      pool float[256][36] aliases [0,36864)
//      invp float[128] at [36864,37376)
// ---------------------------------------------------------------------------
__global__ __launch_bounds__(512, 4) void ckn_main(
    const ushort* __restrict__ xt, const float* __restrict__ invp_g,
    const ushort* __restrict__ wt3, float* __restrict__ out) {
  __shared__ __align__(16) char smem[37376];
  char* const xs = smem;
  float* const pool = (float*)smem;
  float* const invp = (float*)(smem + 36864);

  const int tid = threadIdx.x;
  const int y0 = blockIdx.x;
  const int b = blockIdx.y;

  // pad columns (col 0 and 65, all 4 rows)
  if (tid < 64) {
    const int r4 = tid >> 4, colsel = (tid >> 3) & 1, cblk = tid & 7;
    *(f32x4*)(xs + r4 * 8448 + colsel * 65 * 128 + cblk * 16) =
        (f32x4){0.f, 0.f, 0.f, 0.f};
  }
  if (tid < 128)
    invp[tid] = invp_g[((size_t)b * 64 + 2 * y0 + (tid >> 6)) * 64 + (tid & 63)];

  // stage 4 rows: one 16B global_load_lds per thread per row.
  {
    const int xx = tid >> 3;
    const int c0 = 8 * ((tid & 7) ^ ((xx + 1) & 7));
    const ushort* srcb = xt + ((size_t)b * 64) * 4096 + (size_t)xx * 64 + c0;
#pragma unroll
    for (int r4 = 0; r4 < 4; ++r4) {
      const int y_img = 2 * y0 - 1 + r4;
      char* dst = xs + r4 * 8448 + 128 + tid * 16;
      if ((unsigned)y_img < 64u) {
        const ushort* src = srcb + (size_t)y_img * 4096;
        __builtin_amdgcn_global_load_lds(
            (const __attribute__((address_space(1))) void*)src,
            (__attribute__((address_space(3))) void*)dst, 16, 0, 0);
      } else {
        *(f32x4*)dst = (f32x4){0.f, 0.f, 0.f, 0.f};
      }
    }
  }

  const int lane = tid & 63;
  const int wid = tid >> 6;
  const int wave_m = wid & 1;   // output row within pair (m-half)
  const int wave_n = wid >> 1;  // 64-wide N chunk
  const int lane31 = lane & 31;
  const int hi = lane >> 5;

  // B base in wt3 (ushort elems): fragment (ks, g) is 512 shorts at
  // (ks*8+g)*512; lane reads 8 shorts at n*16 + hi*8.
  const ushort* wb3 = wt3 + (size_t)lane31 * 16 + hi * 8;
  const int g0 = wave_n * 2;  // n-frag 0, g0+1 -> n-frag 1

  // depth-2 B prefetch: ks=0,1 issued BEFORE the barrier (overlaps DMA)
  bf16x8 bq[2][2];
#pragma unroll
  for (int nf = 0; nf < 2; ++nf) {
    bq[0][nf] = *(const bf16x8*)(wb3 + (size_t)(0 * 8 + g0 + nf) * 512);
    bq[1][nf] = *(const bf16x8*)(wb3 + (size_t)(1 * 8 + g0 + nf) * 512);
  }

  __syncthreads();

  f32x16 acc[2][2];
#pragma unroll
  for (int i = 0; i < 2; ++i)
#pragma unroll
    for (int j = 0; j < 2; ++j)
#pragma unroll
      for (int e = 0; e < 16; ++e) acc[i][j][e] = 0.f;

#pragma unroll
  for (int ks = 0; ks < 36; ++ks) {
    const int t9 = ks >> 2;           // (kh,kw) tap index
    const int kh = t9 / 3, kw = t9 % 3;
    const int cb = (ks & 3) * 32 + hi * 16;  // byte offset of 8-c block
    const int r4 = wave_m + kh;
    const int cur = ks & 1;
    bf16x8 afrag[2];
#pragma unroll
    for (int mf = 0; mf < 2; ++mf) {
      const int col = mf * 32 + lane31 + kw;
      const int addr = r4 * 8448 + col * 128 + (cb ^ ((col & 7) << 4));
      afrag[mf] = *(const bf16x8*)(xs + addr);
    }
    __builtin_amdgcn_s_setprio(1);
#pragma unroll
    for (int mf = 0; mf < 2; ++mf)
#pragma unroll
      for (int nf = 0; nf < 2; ++nf)
        acc[mf][nf] = __builtin_amdgcn_mfma_f32_32x32x16_bf16(
            afrag[mf], bq[cur][nf], acc[mf][nf], 0, 0, 0);
    __builtin_amdgcn_s_setprio(0);
    if (ks + 2 < 36) {
#pragma unroll
      for (int nf = 0; nf < 2; ++nf)
        bq[cur][nf] =
            *(const bf16x8*)(wb3 + (size_t)((ks + 2) * 8 + g0 + nf) * 512);
    }
  }

  // epilogue: exp(cos-1), x-pool in-register.
  // reg r of acc[mf][nf]: row = (r&3)+8*(r>>2)+4*hi (x = mf*32+row),
  // col o = wave_n*64 + nf*32 + lane31.
  float ep[2][2][4][2];  // [mf][nf][q][pair]
#pragma unroll
  for (int mf = 0; mf < 2; ++mf) {
#pragma unroll
    for (int q = 0; q < 4; ++q) {
      const f32x4 ip =
          *(const f32x4*)(invp + wave_m * 64 + mf * 32 + 8 * q + 4 * hi);
#pragma unroll
      for (int nf = 0; nf < 2; ++nf) {
        const float e0 = __expf(acc[mf][nf][4 * q + 0] * ip[0] - 1.f);
        const float e1 = __expf(acc[mf][nf][4 * q + 1] * ip[1] - 1.f);
        const float e2 = __expf(acc[mf][nf][4 * q + 2] * ip[2] - 1.f);
        const float e3 = __expf(acc[mf][nf][4 * q + 3] * ip[3] - 1.f);
        ep[mf][nf][q][0] = e0 + e1;
        ep[mf][nf][q][1] = e2 + e3;
      }
    }
  }
  __syncthreads();  // xs reads done; pool may alias

  if (wave_m == 1) {
#pragma unroll
    for (int mf = 0; mf < 2; ++mf)
#pragma unroll
      for (int nf = 0; nf < 2; ++nf)
#pragma unroll
        for (int q = 0; q < 4; ++q) {
          const int o = wave_n * 64 + nf * 32 + lane31;
          const int px = mf * 16 + 4 * q + 2 * hi;
          *(float2*)(pool + o * 36 + px) =
              make_float2(ep[mf][nf][q][0], ep[mf][nf][q][1]);
        }
  }
  __syncthreads();
  if (wave_m == 0) {
#pragma unroll
    for (int mf = 0; mf < 2; ++mf)
#pragma unroll
      for (int nf = 0; nf < 2; ++nf)
#pragma unroll
        for (int q = 0; q < 4; ++q) {
          const int o = wave_n * 64 + nf * 32 + lane31;
          const int px = mf * 16 + 4 * q + 2 * hi;
          float2* p = (float2*)(pool + o * 36 + px);
          const float2 othr = *p;
          *p = make_float2(0.25f * (ep[mf][nf][q][0] + othr.x),
                           0.25f * (ep[mf][nf][q][1] + othr.y));
        }
  }
  __syncthreads();

  // coalesced store: 8 lanes cover one o-row's full 128B
  const size_t obase = (((size_t)b * 256) * 32 + y0) * 32;
#pragma unroll
  for (int j = 0; j < 4; ++j) {
    const int o = j * 64 + (tid >> 3);
    const int ch = (tid & 7) * 4;
    const f32x4 v = *(const f32x4*)(pool + o * 36 + ch);
    *(f32x4*)(out + obase + (size_t)o * 1024 + ch) = v;
  }
}

// ---------------------------------------------------------------------------
// Fallback (round-1 kernel, fused transpose in-block) if ws is too small.
// ---------------------------------------------------------------------------
__global__ __launch_bounds__(512, 4) void ckn_main_v1(
    const float* __restrict__ x, const ushort* __restrict__ wt,
    float* __restrict__ out) {
  __shared__ __align__(16) char smem[43552];
  char* const xs = smem;
  float* const invp = (float*)(smem + 33792);
  float* const cs = (float*)(smem + 34304);
  float* const csp = (float*)(smem + 35360);
  float* const pool = (float*)smem;

  const int tid = threadIdx.x;
  const int y0 = blockIdx.x;
  const int b = blockIdx.y;

  if (tid < 64) {
    const int r4 = tid >> 4, colsel = (tid >> 3) & 1, cblk = tid & 7;
    const int col = colsel * 65;
    *(f32x4*)(xs + r4 * 8448 + col * 128 + cblk * 16) =
        (f32x4){0.f, 0.f, 0.f, 0.f};
  }
  {
    const int xx = tid & 63;
    const int cg = tid >> 6;
    const int col = xx + 1;
    const int sw = (cg * 16) ^ ((col & 7) << 4);
#pragma unroll
    for (int r4 = 0; r4 < 4; ++r4) {
      const int y_img = 2 * y0 - 1 + r4;
      char* dst = xs + r4 * 8448 + col * 128 + sw;
      if ((unsigned)y_img < 64u) {
        const float* src =
            x + (((size_t)b * 64 + cg * 8) * 64 + y_img) * 64 + xx;
        float ss = 0.f;
        union { bf16x8 v; ushort u[8]; } pk;
#pragma unroll
        for (int j = 0; j < 8; ++j) {
          const float f = src[(size_t)j * 4096];
          ss += f * f;
          pk.u[j] = (ushort)bfbits(f);
        }
        *(bf16x8*)dst = pk.v;
        csp[(r4 * 8 + cg) * 64 + xx] = ss;
      } else {
        *(bf16x8*)dst = (bf16x8){0, 0, 0, 0, 0, 0, 0, 0};
        csp[(r4 * 8 + cg) * 64 + xx] = 0.f;
      }
    }
  }
  __syncthreads();
  if (tid < 256) {
    const int r4 = tid >> 6, xc = tid & 63;
    float s = 0.f;
#pragma unroll
    for (int cg = 0; cg < 8; ++cg) s += csp[(r4 * 8 + cg) * 64 + xc];
    cs[r4 * 66 + xc + 1] = s;
  }
  if (tid >= 256 && tid < 264) {
    const int t = tid - 256;
    cs[(t >> 1) * 66 + (t & 1) * 65] = 0.f;
  }
  __syncthreads();
  if (tid < 128) {
    const int ry = tid >> 6, xp = tid & 63;
    float s = 0.f;
#pragma unroll
    for (int dr = 0; dr < 3; ++dr)
#pragma unroll
      for (int dc = 0; dc < 3; ++dc) s += cs[(ry + dr) * 66 + xp + dc];
    invp[tid] = 1.0f / (sqrtf(fmaxf(s, 0.f)) + 1e-8f);
  }
  __syncthreads();

  const int lane = tid & 63;
  const int wid = tid >> 6;
  const int wave_m = wid & 1;
  const int wave_n = wid >> 1;
  const int lane16 = lane & 15;
  const int klane = lane >> 4;
  const int o_base = wave_n * 64;

  f32x4 acc[4][4];
#pragma unroll
  for (int i = 0; i < 4; ++i)
#pragma unroll
    for (int j = 0; j < 4; ++j) acc[i][j] = (f32x4){0.f, 0.f, 0.f, 0.f};
  const ushort* wbase = wt + (o_base + lane16) * 576 + klane * 8;
#pragma unroll
  for (int ks = 0; ks < 18; ++ks) {
    const int t9 = ks >> 1;
    const int kh = t9 / 3, kw = t9 % 3;
    const int cb = (ks & 1) * 64 + klane * 16;
    bf16x8 bfrag[4];
#pragma unroll
    for (int fn = 0; fn < 4; ++fn)
      bfrag[fn] = *(const bf16x8*)(wbase + fn * 16 * 576 + ks * 32);
    const int r4 = wave_m + kh;
#pragma unroll
    for (int fm = 0; fm < 4; ++fm) {
      const int col = fm * 16 + lane16 + kw;
      const int addr = r4 * 8448 + col * 128 + (cb ^ ((col & 7) << 4));
      const bf16x8 afrag = *(const bf16x8*)(xs + addr);
#pragma unroll
      for (int fn = 0; fn < 4; ++fn)
        acc[fm][fn] = __builtin_amdgcn_mfma_f32_16x16x32_bf16(
            afrag, bfrag[fn], acc[fm][fn], 0, 0, 0);
    }
  }
  float ep0[4][4], ep1[4][4];
#pragma unroll
  for (int fm = 0; fm < 4; ++fm) {
    const int m = wave_m * 64 + fm * 16 + klane * 4;
    const f32x4 ip = *(const f32x4*)(invp + m);
#pragma unroll
    for (int fn = 0; fn < 4; ++fn) {
      const f32x4 v = acc[fm][fn];
      const float e0 = __expf(v[0] * ip[0] - 1.f);
      const float e1 = __expf(v[1] * ip[1] - 1.f);
      const float e2 = __expf(v[2] * ip[2] - 1.f);
      const float e3 = __expf(v[3] * ip[3] - 1.f);
      ep0[fm][fn] = e0 + e1;
      ep1[fm][fn] = e2 + e3;
    }
  }
  __syncthreads();
  if (wave_m == 1) {
#pragma unroll
    for (int fm = 0; fm < 4; ++fm) {
      const int ox = fm * 8 + klane * 2;
#pragma unroll
      for (int fn = 0; fn < 4; ++fn) {
        const int o = o_base + fn * 16 + lane16;
        *(float2*)(pool + o * 32 + ox) = make_float2(ep0[fm][fn], ep1[fm][fn]);
      }
    }
  }
  __syncthreads();
  if (wave_m == 0) {
#pragma unroll
    for (int fm = 0; fm < 4; ++fm) {
      const int ox = fm * 8 + klane * 2;
#pragma unroll
      for (int fn = 0; fn < 4; ++fn) {
        const int o = o_base + fn * 16 + lane16;
        const float2 othr = *(const float2*)(pool + o * 32 + ox);
        const float r0 = 0.25f * (ep0[fm][fn] + othr.x);
        const float r1 = 0.25f * (ep1[fm][fn] + othr.y);
        *(float2*)(out + ((((size_t)b * 256 + o) * 32 + y0) * 32 + ox)) =
            make_float2(r0, r1);
      }
    }
  }
}

// ---------------------------------------------------------------------------
extern "C" void kernel_launch(void* const* d_in, const int* in_sizes, int n_in,
                              void* d_out, int out_size, void* d_ws,
                              size_t ws_size, hipStream_t stream) {
  const float* x = (const float*)d_in[0];
  const float* w = (const float*)d_in[1];
  float* out = (float*)d_out;

  const size_t XT_BYTES = 32ull * 64 * 64 * 64 * 2;   // 16,777,216
  const size_t CSS_BYTES = 32ull * 64 * 64 * 4;       //    524,288
  const size_t WT_BYTES = 256ull * 576 * 2;           //    294,912
  const size_t NEED = XT_BYTES + 2 * CSS_BYTES + 2 * WT_BYTES;

  if (ws_size >= NEED) {
    ushort* xt = (ushort*)d_ws;
    float* css = (float*)((char*)d_ws + XT_BYTES);
    float* invp = (float*)((char*)d_ws + XT_BYTES + CSS_BYTES);
    ushort* wt = (ushort*)((char*)d_ws + XT_BYTES + 2 * CSS_BYTES);
    ushort* wt3 = (ushort*)((char*)d_ws + XT_BYTES + 2 * CSS_BYTES + WT_BYTES);

    wnorm_kernel<<<dim3(256), dim3(64), 0, stream>>>(w, wt, wt3);
    xprep_kernel<<<dim3(64, 32), dim3(256), 0, stream>>>(x, xt, css);
    invp_kernel<<<dim3(64, 32), dim3(64), 0, stream>>>(css, invp);
    ckn_main<<<dim3(32, 32), dim3(512), 0, stream>>>(xt, invp, wt3, out);
  } else {
    ushort* wt = (ushort*)d_ws;
    ushort* wt3 = wt + 256 * 576;
    if (ws_size >= 2 * WT_BYTES) {
      wnorm_kernel<<<dim3(256), dim3(64), 0, stream>>>(w, wt, wt3);
      ckn_main_v1<<<dim3(32, 32), dim3(512), 0, stream>>>(x, wt, out);
    }
  }
}

// Round 6
// 65.814 us; speedup vs baseline: 8.3416x; 1.0848x over previous
//
#include <hip/hip_runtime.h>
#include <hip/hip_bf16.h>

typedef __attribute__((ext_vector_type(8))) short bf16x8;
typedef __attribute__((ext_vector_type(4))) float f32x4;
typedef __attribute__((ext_vector_type(16))) float f32x16;
typedef __attribute__((ext_vector_type(4))) unsigned u32x4;

__device__ __forceinline__ unsigned bfbits(float v) {
  __hip_bfloat16 h = __float2bfloat16(v);
  return (unsigned)*reinterpret_cast<unsigned short*>(&h);
}

// granule swizzle: g(col) = (col&7) ^ (((col>>3)&3)<<1)
__device__ __forceinline__ int gswz(int col) {
  return (col & 7) ^ (((col >> 3) & 3) << 1);
}

// ---------------------------------------------------------------------------
// Weight normalization body: one 64-lane wave handles one output row o.
//  wt  [o][(kh*3+kw)*64 + c]        (legacy 16x16 layout, fallback kernel)
//  wt3 [ks][g=o/32][n=o%32][k16]    (32x32x16 fragment-major)
// ---------------------------------------------------------------------------
__device__ __forceinline__ void wnorm_one(const float* __restrict__ w,
                                          ushort* __restrict__ wt,
                                          ushort* __restrict__ wt3,
                                          int o, int c) {
  float v[9];
  float ss = 0.f;
  const float* row = w + o * 576 + c * 9;
#pragma unroll
  for (int j = 0; j < 9; ++j) { v[j] = row[j]; ss += v[j] * v[j]; }
#pragma unroll
  for (int off = 32; off > 0; off >>= 1) ss += __shfl_xor(ss, off);
  const float inv = 1.0f / fmaxf(sqrtf(ss), 1e-12f);
  const int g = o >> 5, n = o & 31;
#pragma unroll
  for (int j = 0; j < 9; ++j) {
    const ushort bv = (ushort)bfbits(v[j] * inv);
    wt[o * 576 + j * 64 + c] = bv;
    const int ks = j * 4 + (c >> 4);
    wt3[((ks * 8 + g) * 32 + n) * 16 + (c & 15)] = bv;
  }
}

__global__ void wnorm_kernel(const float* __restrict__ w,
                             ushort* __restrict__ wt,
                             ushort* __restrict__ wt3) {
  wnorm_one(w, wt, wt3, blockIdx.x, threadIdx.x);
}

// ---------------------------------------------------------------------------
// Kernel 2: blockIdx.y < 32 : transpose+convert x [B][C][H][W] fp32 ->
//   xt [B][H][W][C] bf16 and css[B][H][W] = sum_c x^2. One block per (y, b).
// blockIdx.y == 32 : fused weight normalization (4 waves -> 4 o rows).
// ---------------------------------------------------------------------------
__global__ __launch_bounds__(256, 8) void xprep_kernel(
    const float* __restrict__ x, ushort* __restrict__ xt,
    float* __restrict__ css, const float* __restrict__ w,
    ushort* __restrict__ wt, ushort* __restrict__ wt3) {
  __shared__ __align__(16) unsigned tile[64 * 33];  // [x][c2] padded stride 33
  __shared__ __align__(16) float cssp[4 * 64];
  const int t = threadIdx.x;
  if (blockIdx.y == 32) {
    wnorm_one(w, wt, wt3, blockIdx.x * 4 + (t >> 6), t & 63);
    return;
  }
  const int y = blockIdx.x, b = blockIdx.y;
  const int c = t >> 2, m = t & 3;
  const int lane = t & 63, wv = t >> 6;

  const float* src = x + (((size_t)b * 64 + c) * 64 + y) * 64 + m * 4;
  float f[16];
#pragma unroll
  for (int j4 = 0; j4 < 4; ++j4) {
    const f32x4 v = *(const f32x4*)(src + j4 * 16);
#pragma unroll
    for (int k = 0; k < 4; ++k) f[j4 * 4 + k] = v[k];
  }
  float s[16];
#pragma unroll
  for (int j = 0; j < 16; ++j) {
    float v = f[j] * f[j];
    v += __shfl_xor(v, 4);
    v += __shfl_xor(v, 8);
    v += __shfl_xor(v, 16);
    v += __shfl_xor(v, 32);
    s[j] = v;
  }
  if (lane < 4) {
#pragma unroll
    for (int j4 = 0; j4 < 4; ++j4) {
      f32x4 v = {s[j4 * 4], s[j4 * 4 + 1], s[j4 * 4 + 2], s[j4 * 4 + 3]};
      *(f32x4*)(cssp + wv * 64 + j4 * 16 + lane * 4) = v;
    }
  }
  const int parity = c & 1;
  const int c2 = c >> 1;
#pragma unroll
  for (int j = 0; j < 16; ++j) {
    const float pf = __shfl_xor(f[j], 4);
    const bool mine = parity ? (j >= 8) : (j < 8);
    if (mine) {
      const unsigned dw = parity ? (bfbits(pf) | (bfbits(f[j]) << 16))
                                 : (bfbits(f[j]) | (bfbits(pf) << 16));
      const int px = (j >> 2) * 16 + m * 4 + (j & 3);
      tile[px * 33 + c2] = dw;
    }
  }
  __syncthreads();
  {
    const int xr = t >> 2, q = t & 3;
    unsigned d[8];
#pragma unroll
    for (int i = 0; i < 8; ++i) d[i] = tile[xr * 33 + q * 8 + i];
    ushort* dst = xt + (((size_t)b * 64 + y) * 64 + xr) * 64 + q * 16;
    u32x4 v0 = {d[0], d[1], d[2], d[3]};
    u32x4 v1 = {d[4], d[5], d[6], d[7]};
    *(u32x4*)dst = v0;
    *(u32x4*)(dst + 8) = v1;
  }
  if (t < 64) {
    const float sum = cssp[t] + cssp[64 + t] + cssp[128 + t] + cssp[192 + t];
    css[((size_t)b * 64 + y) * 64 + t] = sum;
  }
}

// ---------------------------------------------------------------------------
// Main kernel: one block per (image b, output row-pair y0). A staged in LDS
// (global_load_lds, source pre-swizzled with gswz); B from wt3 (contiguous
// 1KB/wave fragments, depth-2 register prefetch); 32x32x16 MFMA (M=128 x
// N=256 x K=576); invp computed in-kernel from css; exp epilogue fused with
// the pool writes; 2x2 pool via transposed LDS pool; coalesced store.
//
// __launch_bounds__(512, 4): 128-reg cap (acc = 64 AGPR); >128 spills.
// Occupancy is reg-capped at 16 waves/CU, LDS sized to match (2 blocks/CU).
//
// LDS: xs   [4 rows][66 cols][128B], granule = cb8 ^ gswz(col)   [0, 33792)
//      pool [32 px][260 floats] (transposed, b32-spread)     [33792, 67072)
//      invp float[128]                                       [67072, 67584)
// ---------------------------------------------------------------------------
__global__ __launch_bounds__(512, 4) void ckn_main(
    const ushort* __restrict__ xt, const float* __restrict__ css,
    const ushort* __restrict__ wt3, float* __restrict__ out) {
  __shared__ __align__(16) char smem[67584];
  char* const xs = smem;
  float* const pool = (float*)(smem + 33792);
  float* const invp = (float*)(smem + 67072);
  const int PS = 260;

  const int tid = threadIdx.x;
  const int y0 = blockIdx.x;
  const int b = blockIdx.y;

  // ---- invp from css (rows 2y0-1..2y0+2, clamped), written pre-barrier ----
  if (tid < 128) {
    const int ry = tid >> 6, xx = tid & 63;
    const int yc = 2 * y0 + ry;
    float s = 0.f;
#pragma unroll
    for (int dy = -1; dy <= 1; ++dy) {
      const int yy = yc + dy;
      if ((unsigned)yy < 64u) s += css[((size_t)b * 64 + yy) * 64 + xx];
    }
    const float sl = __shfl_up(s, 1);
    const float sr = __shfl_down(s, 1);
    const float tot = s + ((xx > 0) ? sl : 0.f) + ((xx < 63) ? sr : 0.f);
    invp[tid] = 1.0f / (sqrtf(fmaxf(tot, 0.f)) + 1e-8f);
  }

  // ---- pad columns (col 0 and 65, all 4 rows) ----
  if (tid < 64) {
    const int r4 = tid >> 4, colsel = (tid >> 3) & 1, cblk = tid & 7;
    *(f32x4*)(xs + r4 * 8448 + colsel * 65 * 128 + cblk * 16) =
        (f32x4){0.f, 0.f, 0.f, 0.f};
  }

  // ---- stage 4 rows: one 16B global_load_lds per thread per row ----
  // LDS dest linear; source address carries the inverse granule swizzle.
  {
    const int xx = tid >> 3;
    const int c0 = 8 * ((tid & 7) ^ gswz(xx + 1));
    const ushort* srcb = xt + ((size_t)b * 64) * 4096 + (size_t)xx * 64 + c0;
#pragma unroll
    for (int r4 = 0; r4 < 4; ++r4) {
      const int y_img = 2 * y0 - 1 + r4;
      char* dst = xs + r4 * 8448 + 128 + tid * 16;
      if ((unsigned)y_img < 64u) {
        const ushort* src = srcb + (size_t)y_img * 4096;
        __builtin_amdgcn_global_load_lds(
            (const __attribute__((address_space(1))) void*)src,
            (__attribute__((address_space(3))) void*)dst, 16, 0, 0);
      } else {
        *(f32x4*)dst = (f32x4){0.f, 0.f, 0.f, 0.f};
      }
    }
  }

  const int lane = tid & 63;
  const int wid = tid >> 6;
  const int wave_m = wid & 1;   // output row within pair (m-half)
  const int wave_n = wid >> 1;  // 64-wide N chunk
  const int lane31 = lane & 31;
  const int hi = lane >> 5;

  // B base in wt3 (ushort elems): fragment (ks, g) is 512 shorts at
  // (ks*8+g)*512; lane reads 8 shorts at n*16 + hi*8.
  const ushort* wb3 = wt3 + (size_t)lane31 * 16 + hi * 8;
  const int g0 = wave_n * 2;

  // depth-2 B prefetch: ks=0,1 issued BEFORE the barrier (overlaps DMA)
  bf16x8 bq[2][2];
#pragma unroll
  for (int nf = 0; nf < 2; ++nf) {
    bq[0][nf] = *(const bf16x8*)(wb3 + (size_t)(0 * 8 + g0 + nf) * 512);
    bq[1][nf] = *(const bf16x8*)(wb3 + (size_t)(1 * 8 + g0 + nf) * 512);
  }

  // precomputed A addresses: PH[mf][kw] = (col*128 + gswz(col)<<4) ^ hi16;
  // per-step addr = (wave_m+kh)*8448 + (PH ^ ((ks&3)<<5))   (bits 4-6 XOR)
  const int hi16 = hi << 4;
  int PH[2][3];
#pragma unroll
  for (int mf = 0; mf < 2; ++mf)
#pragma unroll
    for (int kw = 0; kw < 3; ++kw) {
      const int col = mf * 32 + lane31 + kw;
      PH[mf][kw] = (col * 128 + (gswz(col) << 4)) ^ hi16;
    }
  const int rb0 = wave_m * 8448;

  __syncthreads();

  f32x16 acc[2][2];
#pragma unroll
  for (int i = 0; i < 2; ++i)
#pragma unroll
    for (int j = 0; j < 2; ++j)
#pragma unroll
      for (int e = 0; e < 16; ++e) acc[i][j][e] = 0.f;

#pragma unroll
  for (int ks = 0; ks < 36; ++ks) {
    const int t9 = ks >> 2;
    const int kh = t9 / 3, kw = t9 % 3;
    const int ksc = (ks & 3) << 5;
    const int cur = ks & 1;
    bf16x8 afrag[2];
#pragma unroll
    for (int mf = 0; mf < 2; ++mf)
      afrag[mf] = *(const bf16x8*)(xs + rb0 + kh * 8448 + (PH[mf][kw] ^ ksc));
    __builtin_amdgcn_s_setprio(1);
#pragma unroll
    for (int mf = 0; mf < 2; ++mf)
#pragma unroll
      for (int nf = 0; nf < 2; ++nf)
        acc[mf][nf] = __builtin_amdgcn_mfma_f32_32x32x16_bf16(
            afrag[mf], bq[cur][nf], acc[mf][nf], 0, 0, 0);
    __builtin_amdgcn_s_setprio(0);
    if (ks + 2 < 36) {
#pragma unroll
      for (int nf = 0; nf < 2; ++nf)
        bq[cur][nf] =
            *(const bf16x8*)(wb3 + (size_t)((ks + 2) * 8 + g0 + nf) * 512);
    }
  }

  // ---- epilogue: exp(cos-1) fused with pool writes (transposed pool) ----
  // acc reg r: x = mf*32 + (r&3) + 8*(r>>2) + 4*hi ; o = wave_n*64+nf*32+lane31
  if (wave_m == 1) {
#pragma unroll
    for (int mf = 0; mf < 2; ++mf)
#pragma unroll
      for (int q = 0; q < 4; ++q) {
        const f32x4 ip = *(const f32x4*)(invp + 64 + mf * 32 + 8 * q + 4 * hi);
        const int px = mf * 16 + 4 * q + 2 * hi;
#pragma unroll
        for (int nf = 0; nf < 2; ++nf) {
          const int o = wave_n * 64 + nf * 32 + lane31;
          const float e0 = __expf(acc[mf][nf][4 * q + 0] * ip[0] - 1.f);
          const float e1 = __expf(acc[mf][nf][4 * q + 1] * ip[1] - 1.f);
          const float e2 = __expf(acc[mf][nf][4 * q + 2] * ip[2] - 1.f);
          const float e3 = __expf(acc[mf][nf][4 * q + 3] * ip[3] - 1.f);
          pool[px * PS + o] = e0 + e1;
          pool[(px + 1) * PS + o] = e2 + e3;
        }
      }
  }
  __syncthreads();
  if (wave_m == 0) {
#pragma unroll
    for (int mf = 0; mf < 2; ++mf)
#pragma unroll
      for (int q = 0; q < 4; ++q) {
        const f32x4 ip = *(const f32x4*)(invp + mf * 32 + 8 * q + 4 * hi);
        const int px = mf * 16 + 4 * q + 2 * hi;
#pragma unroll
        for (int nf = 0; nf < 2; ++nf) {
          const int o = wave_n * 64 + nf * 32 + lane31;
          const float e0 = __expf(acc[mf][nf][4 * q + 0] * ip[0] - 1.f);
          const float e1 = __expf(acc[mf][nf][4 * q + 1] * ip[1] - 1.f);
          const float e2 = __expf(acc[mf][nf][4 * q + 2] * ip[2] - 1.f);
          const float e3 = __expf(acc[mf][nf][4 * q + 3] * ip[3] - 1.f);
          pool[px * PS + o] = 0.25f * (pool[px * PS + o] + e0 + e1);
          pool[(px + 1) * PS + o] = 0.25f * (pool[(px + 1) * PS + o] + e2 + e3);
        }
      }
  }
  __syncthreads();

  // ---- coalesced store: 8 lanes cover one o-row's full 128B ----
  const size_t obase = (((size_t)b * 256) * 32 + y0) * 32;
#pragma unroll
  for (int j = 0; j < 4; ++j) {
    const int o = j * 64 + (tid >> 3);
    const int ch = (tid & 7) * 4;
    const f32x4 v = {pool[(ch + 0) * PS + o], pool[(ch + 1) * PS + o],
                     pool[(ch + 2) * PS + o], pool[(ch + 3) * PS + o]};
    *(f32x4*)(out + obase + (size_t)o * 1024 + ch) = v;
  }
}

// ---------------------------------------------------------------------------
// Fallback (round-1 kernel, fused transpose in-block) if ws is too small.
// ---------------------------------------------------------------------------
__global__ __launch_bounds__(512, 4) void ckn_main_v1(
    const float* __restrict__ x, const ushort* __restrict__ wt,
    float* __restrict__ out) {
  __shared__ __align__(16) char smem[43552];
  char* const xs = smem;
  float* const invp = (float*)(smem + 33792);
  float* const cs = (float*)(smem + 34304);
  float* const csp = (float*)(smem + 35360);
  float* const pool = (float*)smem;

  const int tid = threadIdx.x;
  const int y0 = blockIdx.x;
  const int b = blockIdx.y;

  if (tid < 64) {
    const int r4 = tid >> 4, colsel = (tid >> 3) & 1, cblk = tid & 7;
    const int col = colsel * 65;
    *(f32x4*)(xs + r4 * 8448 + col * 128 + cblk * 16) =
        (f32x4){0.f, 0.f, 0.f, 0.f};
  }
  {
    const int xx = tid & 63;
    const int cg = tid >> 6;
    const int col = xx + 1;
    const int sw = (cg * 16) ^ ((col & 7) << 4);
#pragma unroll
    for (int r4 = 0; r4 < 4; ++r4) {
      const int y_img = 2 * y0 - 1 + r4;
      char* dst = xs + r4 * 8448 + col * 128 + sw;
      if ((unsigned)y_img < 64u) {
        const float* src =
            x + (((size_t)b * 64 + cg * 8) * 64 + y_img) * 64 + xx;
        float ss = 0.f;
        union { bf16x8 v; ushort u[8]; } pk;
#pragma unroll
        for (int j = 0; j < 8; ++j) {
          const float f = src[(size_t)j * 4096];
          ss += f * f;
          pk.u[j] = (ushort)bfbits(f);
        }
        *(bf16x8*)dst = pk.v;
        csp[(r4 * 8 + cg) * 64 + xx] = ss;
      } else {
        *(bf16x8*)dst = (bf16x8){0, 0, 0, 0, 0, 0, 0, 0};
        csp[(r4 * 8 + cg) * 64 + xx] = 0.f;
      }
    }
  }
  __syncthreads();
  if (tid < 256) {
    const int r4 = tid >> 6, xc = tid & 63;
    float s = 0.f;
#pragma unroll
    for (int cg = 0; cg < 8; ++cg) s += csp[(r4 * 8 + cg) * 64 + xc];
    cs[r4 * 66 + xc + 1] = s;
  }
  if (tid >= 256 && tid < 264) {
    const int t = tid - 256;
    cs[(t >> 1) * 66 + (t & 1) * 65] = 0.f;
  }
  __syncthreads();
  if (tid < 128) {
    const int ry = tid >> 6, xp = tid & 63;
    float s = 0.f;
#pragma unroll
    for (int dr = 0; dr < 3; ++dr)
#pragma unroll
      for (int dc = 0; dc < 3; ++dc) s += cs[(ry + dr) * 66 + xp + dc];
    invp[tid] = 1.0f / (sqrtf(fmaxf(s, 0.f)) + 1e-8f);
  }
  __syncthreads();

  const int lane = tid & 63;
  const int wid = tid >> 6;
  const int wave_m = wid & 1;
  const int wave_n = wid >> 1;
  const int lane16 = lane & 15;
  const int klane = lane >> 4;
  const int o_base = wave_n * 64;

  f32x4 acc[4][4];
#pragma unroll
  for (int i = 0; i < 4; ++i)
#pragma unroll
    for (int j = 0; j < 4; ++j) acc[i][j] = (f32x4){0.f, 0.f, 0.f, 0.f};
  const ushort* wbase = wt + (o_base + lane16) * 576 + klane * 8;
#pragma unroll
  for (int ks = 0; ks < 18; ++ks) {
    const int t9 = ks >> 1;
    const int kh = t9 / 3, kw = t9 % 3;
    const int cb = (ks & 1) * 64 + klane * 16;
    bf16x8 bfrag[4];
#pragma unroll
    for (int fn = 0; fn < 4; ++fn)
      bfrag[fn] = *(const bf16x8*)(wbase + fn * 16 * 576 + ks * 32);
    const int r4 = wave_m + kh;
#pragma unroll
    for (int fm = 0; fm < 4; ++fm) {
      const int col = fm * 16 + lane16 + kw;
      const int addr = r4 * 8448 + col * 128 + (cb ^ ((col & 7) << 4));
      const bf16x8 afrag = *(const bf16x8*)(xs + addr);
#pragma unroll
      for (int fn = 0; fn < 4; ++fn)
        acc[fm][fn] = __builtin_amdgcn_mfma_f32_16x16x32_bf16(
            afrag, bfrag[fn], acc[fm][fn], 0, 0, 0);
    }
  }
  float ep0[4][4], ep1[4][4];
#pragma unroll
  for (int fm = 0; fm < 4; ++fm) {
    const int m = wave_m * 64 + fm * 16 + klane * 4;
    const f32x4 ip = *(const f32x4*)(invp + m);
#pragma unroll
    for (int fn = 0; fn < 4; ++fn) {
      const f32x4 v = acc[fm][fn];
      const float e0 = __expf(v[0] * ip[0] - 1.f);
      const float e1 = __expf(v[1] * ip[1] - 1.f);
      const float e2 = __expf(v[2] * ip[2] - 1.f);
      const float e3 = __expf(v[3] * ip[3] - 1.f);
      ep0[fm][fn] = e0 + e1;
      ep1[fm][fn] = e2 + e3;
    }
  }
  __syncthreads();
  if (wave_m == 1) {
#pragma unroll
    for (int fm = 0; fm < 4; ++fm) {
      const int ox = fm * 8 + klane * 2;
#pragma unroll
      for (int fn = 0; fn < 4; ++fn) {
        const int o = o_base + fn * 16 + lane16;
        *(float2*)(pool + o * 32 + ox) = make_float2(ep0[fm][fn], ep1[fm][fn]);
      }
    }
  }
  __syncthreads();
  if (wave_m == 0) {
#pragma unroll
    for (int fm = 0; fm < 4; ++fm) {
      const int ox = fm * 8 + klane * 2;
#pragma unroll
      for (int fn = 0; fn < 4; ++fn) {
        const int o = o_base + fn * 16 + lane16;
        const float2 othr = *(const float2*)(pool + o * 32 + ox);
        const float r0 = 0.25f * (ep0[fm][fn] + othr.x);
        const float r1 = 0.25f * (ep1[fm][fn] + othr.y);
        *(float2*)(out + ((((size_t)b * 256 + o) * 32 + y0) * 32 + ox)) =
            make_float2(r0, r1);
      }
    }
  }
}

// ---------------------------------------------------------------------------
extern "C" void kernel_launch(void* const* d_in, const int* in_sizes, int n_in,
                              void* d_out, int out_size, void* d_ws,
                              size_t ws_size, hipStream_t stream) {
  const float* x = (const float*)d_in[0];
  const float* w = (const float*)d_in[1];
  float* out = (float*)d_out;

  const size_t XT_BYTES = 32ull * 64 * 64 * 64 * 2;   // 16,777,216
  const size_t CSS_BYTES = 32ull * 64 * 64 * 4;       //    524,288
  const size_t WT_BYTES = 256ull * 576 * 2;           //    294,912
  const size_t NEED = XT_BYTES + CSS_BYTES + 2 * WT_BYTES;

  if (ws_size >= NEED) {
    ushort* xt = (ushort*)d_ws;
    float* css = (float*)((char*)d_ws + XT_BYTES);
    ushort* wt = (ushort*)((char*)d_ws + XT_BYTES + CSS_BYTES);
    ushort* wt3 = (ushort*)((char*)d_ws + XT_BYTES + CSS_BYTES + WT_BYTES);

    xprep_kernel<<<dim3(64, 33), dim3(256), 0, stream>>>(x, xt, css, w, wt,
                                                         wt3);
    ckn_main<<<dim3(32, 32), dim3(512), 0, stream>>>(xt, css, wt3, out);
  } else {
    ushort* wt = (ushort*)d_ws;
    ushort* wt3 = wt + 256 * 576;
    if (ws_size >= 2 * WT_BYTES) {
      wnorm_kernel<<<dim3(256), dim3(64), 0, stream>>>(w, wt, wt3);
      ckn_main_v1<<<dim3(32, 32), dim3(512), 0, stream>>>(x, wt, out);
    }
  }
}